// Round 2
// 959.856 us; speedup vs baseline: 1.0362x; 1.0362x over previous
//
#include <hip/hip_runtime.h>
#include <math.h>

#define N_NODES 50000
#define N_EDGES 600000
#define N_GRAPHS 512
#define F_IN 128
#define D_HID 128
#define EDIM 384
#define M_ALL (N_NODES + N_GRAPHS)  // node rows + appended pooled graph rows

typedef __attribute__((ext_vector_type(8))) short bf16x8;
typedef __attribute__((ext_vector_type(4))) float f32x4;

static __device__ __forceinline__ float wave_reduce_sum(float s) {
#pragma unroll
  for (int off = 32; off > 0; off >>= 1) s += __shfl_xor(s, off, 64);
  return s;
}

static __device__ __forceinline__ short f2b(float f) {
  unsigned u = __float_as_uint(f);
  unsigned r = (u + 0x7FFFu + ((u >> 16) & 1u)) >> 16;
  return (short)r;
}

static __device__ __forceinline__ float b2f(short s) {
  return __uint_as_float(((unsigned)(unsigned short)s) << 16);
}

// ---------------- graph preprocessing ----------------

__global__ void hist_kernel(const int* __restrict__ dst, int* __restrict__ cnt) {
  int i = blockIdx.x * blockDim.x + threadIdx.x;
  if (i < N_EDGES) atomicAdd(&cnt[dst[i]], 1);
}

__global__ void gptr_kernel(const int* __restrict__ batch, int* __restrict__ gptr) {
  int g = blockIdx.x * blockDim.x + threadIdx.x;
  if (g > N_GRAPHS) return;
  int lo = 0, hi = N_NODES;
  while (lo < hi) { int mid = (lo + hi) >> 1; if (batch[mid] < g) lo = mid + 1; else hi = mid; }
  gptr[g] = lo;
}

// ---- 3-phase parallel exclusive scan of cnt -> row_ptr, cursor ----

#define SCAN_BS 256
#define SCAN_NB ((N_NODES + SCAN_BS - 1) / SCAN_BS)  // 196

__global__ __launch_bounds__(SCAN_BS) void scan1_kernel(const int* __restrict__ cnt,
                                                        int* __restrict__ row_ptr,
                                                        int* __restrict__ bsum) {
  __shared__ int wsum[4];
  int tid = threadIdx.x, lane = tid & 63, wid = tid >> 6;
  int idx = blockIdx.x * SCAN_BS + tid;
  int v = (idx < N_NODES) ? cnt[idx] : 0;
  int x = v;
#pragma unroll
  for (int off = 1; off < 64; off <<= 1) {
    int t = __shfl_up(x, off, 64);
    if (lane >= off) x += t;
  }
  if (lane == 63) wsum[wid] = x;
  __syncthreads();
  int pre = 0, tot = 0;
#pragma unroll
  for (int w = 0; w < 4; ++w) { int s = wsum[w]; tot += s; if (w < wid) pre += s; }
  if (idx < N_NODES) row_ptr[idx + 1] = x + pre;  // block-local inclusive
  if (tid == 0) bsum[blockIdx.x] = tot;
}

__global__ __launch_bounds__(SCAN_BS) void scan2_kernel(const int* __restrict__ bsum,
                                                        int* __restrict__ boffs) {
  __shared__ int wsum[4];
  int tid = threadIdx.x, lane = tid & 63, wid = tid >> 6;
  int v = (tid < SCAN_NB) ? bsum[tid] : 0;
  int x = v;
#pragma unroll
  for (int off = 1; off < 64; off <<= 1) {
    int t = __shfl_up(x, off, 64);
    if (lane >= off) x += t;
  }
  if (lane == 63) wsum[wid] = x;
  __syncthreads();
  int pre = 0;
#pragma unroll
  for (int w = 0; w < 4; ++w) { int s = wsum[w]; if (w < wid) pre += s; }
  if (tid < SCAN_NB) boffs[tid] = x + pre - v;  // exclusive
}

__global__ __launch_bounds__(SCAN_BS) void scan3_kernel(const int* __restrict__ cnt,
                                                        const int* __restrict__ boffs,
                                                        int* __restrict__ row_ptr,
                                                        int* __restrict__ cursor) {
  int idx = blockIdx.x * SCAN_BS + threadIdx.x;
  if (idx >= N_NODES) return;
  int val = row_ptr[idx + 1] + boffs[blockIdx.x];
  row_ptr[idx + 1] = val;
  cursor[idx] = val - cnt[idx];
  if (idx == 0) row_ptr[0] = 0;
}

__global__ void dinv_kernel(const int* __restrict__ cnt, float* __restrict__ dinv) {
  int i = blockIdx.x * blockDim.x + threadIdx.x;
  if (i < N_NODES) dinv[i] = 1.0f / sqrtf((float)(cnt[i] + 1));
}

__global__ void scatter_kernel(const int* __restrict__ src, const int* __restrict__ dst,
                               const float* __restrict__ dinv, int* __restrict__ cursor,
                               int* __restrict__ col, float* __restrict__ ew) {
  int e = blockIdx.x * blockDim.x + threadIdx.x;
  if (e >= N_EDGES) return;
  int s = src[e], d = dst[e];
  int pos = atomicAdd(&cursor[d], 1);
  col[pos] = s;
  ew[pos] = dinv[s] * dinv[d];
}

// ---------------- combined weight convert+transpose (10 matrices, 1 launch) ----

struct WcSeg { const float* W; short* Wt; int K; int Nc; };
struct WcArgs { WcSeg seg[10]; };

__global__ void wconv_all_kernel(WcArgs a) {
  int sidx = blockIdx.y;
  WcSeg s = a.seg[sidx];
  int i = blockIdx.x * blockDim.x + threadIdx.x;
  if (i >= s.K * s.Nc) return;
  int k = i / s.Nc, n = i - k * s.Nc;
  s.Wt[(size_t)n * s.K + k] = f2b(s.W[i]);
}

// ---------------- logmap0 (wave per row of 128) -> bf16 ----------------

__global__ __launch_bounds__(256) void logmap_kernel(const float* __restrict__ x,
                                                     short* __restrict__ out) {
  int row = blockIdx.x * 4 + (threadIdx.x >> 6);
  int lane = threadIdx.x & 63;
  if (row >= N_NODES) return;
  float2 v = *(const float2*)(x + (size_t)row * F_IN + lane * 2);
  float s = wave_reduce_sum(v.x * v.x + v.y * v.y);
  float n = sqrtf(s);
  float nc = fmaxf(n, 1e-15f);
  float f = atanhf(fminf(nc, 0.9999999f)) / nc;
  short2 o; o.x = f2b(v.x * f); o.y = f2b(v.y * f);
  *(short2*)(out + (size_t)row * F_IN + lane * 2) = o;
}

// ---------------- CSR aggregation on bf16 features (pre-GEMM, linearity swap) --
// Xa[node][0..127] = sum_j ew[j] * Xin[col[j]] + (dinv^2) * Xin[node]
// One wave per node: 64 lanes x short2 = one 256B row per access. 4 nodes/block.

__global__ __launch_bounds__(256) void agg_b_kernel(const short* __restrict__ Xin, int lda,
                                                    const float* __restrict__ dinv,
                                                    const int* __restrict__ row_ptr,
                                                    const int* __restrict__ col,
                                                    const float* __restrict__ ew,
                                                    short* __restrict__ Xa) {
  int node = blockIdx.x * 4 + (threadIdx.x >> 6);
  int lane = threadIdx.x & 63;
  if (node >= N_NODES) return;
  float di = dinv[node];
  unsigned sv = *(const unsigned*)(Xin + (size_t)node * lda + lane * 2);
  float w_self = di * di;
  float acc0 = b2f((short)(sv & 0xffffu)) * w_self;
  float acc1 = b2f((short)(sv >> 16)) * w_self;
  int s = row_ptr[node], e = row_ptr[node + 1];
  int j = s;
  for (; j + 4 <= e; j += 4) {
    int c0 = col[j], c1 = col[j + 1], c2 = col[j + 2], c3 = col[j + 3];
    float w0 = ew[j], w1 = ew[j + 1], w2 = ew[j + 2], w3 = ew[j + 3];
    unsigned v0 = *(const unsigned*)(Xin + (size_t)c0 * lda + lane * 2);
    unsigned v1 = *(const unsigned*)(Xin + (size_t)c1 * lda + lane * 2);
    unsigned v2 = *(const unsigned*)(Xin + (size_t)c2 * lda + lane * 2);
    unsigned v3 = *(const unsigned*)(Xin + (size_t)c3 * lda + lane * 2);
    acc0 += b2f((short)(v0 & 0xffffu)) * w0; acc1 += b2f((short)(v0 >> 16)) * w0;
    acc0 += b2f((short)(v1 & 0xffffu)) * w1; acc1 += b2f((short)(v1 >> 16)) * w1;
    acc0 += b2f((short)(v2 & 0xffffu)) * w2; acc1 += b2f((short)(v2 >> 16)) * w2;
    acc0 += b2f((short)(v3 & 0xffffu)) * w3; acc1 += b2f((short)(v3 >> 16)) * w3;
  }
  for (; j < e; ++j) {
    float w = ew[j];
    unsigned v = *(const unsigned*)(Xin + (size_t)col[j] * lda + lane * 2);
    acc0 += b2f((short)(v & 0xffffu)) * w; acc1 += b2f((short)(v >> 16)) * w;
  }
  short2 o; o.x = f2b(acc0); o.y = f2b(acc1);
  *(short2*)(Xa + (size_t)node * 128 + lane * 2) = o;
}

// ---------------- bf16 MFMA GEMM: C[M,Nc] = A[M,K] @ Bt[Nc,K]^T ----------------
// A row stride lda (shorts); Bt row-major [Nc][K]. 128x128 tile, 4 waves (2x2).
// Nc multiple of 128; K multiple of 32.
// Epilogue: optional bias[cc] add + relu.
// Output: bf16 to Cb (row stride ldc) if Cb != null; else fp32 row-split:
// rows < split -> Cf (stride Nc), rows >= split -> Cf2 + (row - split)*Nc.

#define LDK 40  // 32 + 8 pad shorts

__global__ __launch_bounds__(256) void mfma_gemm_kernel(const short* __restrict__ A, int lda,
                                                        const short* __restrict__ Bt,
                                                        int M, int Nc, int K,
                                                        int do_relu,
                                                        const float* __restrict__ bias,
                                                        float* __restrict__ Cf,
                                                        float* __restrict__ Cf2, int split,
                                                        short* __restrict__ Cb, int ldc) {
  __shared__ __align__(16) short As[128 * LDK];
  __shared__ __align__(16) short Bs[128 * LDK];
  int tid = threadIdx.x;
  int wave = tid >> 6, lane = tid & 63;
  int wr = (wave >> 1) * 64, wc = (wave & 1) * 64;
  int q = lane >> 4, m = lane & 15;
  int row0 = blockIdx.x * 128, col0 = blockIdx.y * 128;
  f32x4 acc[4][4] = {};
  for (int k0 = 0; k0 < K; k0 += 32) {
#pragma unroll
    for (int p = 0; p < 2; ++p) {
      int idx = p * 256 + tid;      // 0..511
      int r = idx >> 2, kc = (idx & 3) * 8;
      int gr = row0 + r;
      float4 v = make_float4(0.f, 0.f, 0.f, 0.f);
      if (gr < M) v = *(const float4*)(A + (size_t)gr * lda + k0 + kc);
      *(float4*)(As + r * LDK + kc) = v;
      float4 w = *(const float4*)(Bt + (size_t)(col0 + r) * K + k0 + kc);
      *(float4*)(Bs + r * LDK + kc) = w;
    }
    __syncthreads();
    bf16x8 af[4], bfr[4];
#pragma unroll
    for (int i = 0; i < 4; ++i) {
      af[i]  = *(const bf16x8*)(As + (wr + i * 16 + m) * LDK + q * 8);
      bfr[i] = *(const bf16x8*)(Bs + (wc + i * 16 + m) * LDK + q * 8);
    }
#pragma unroll
    for (int i = 0; i < 4; ++i)
#pragma unroll
      for (int j = 0; j < 4; ++j)
        acc[i][j] = __builtin_amdgcn_mfma_f32_16x16x32_bf16(af[i], bfr[j], acc[i][j], 0, 0, 0);
    __syncthreads();
  }
#pragma unroll
  for (int i = 0; i < 4; ++i) {
#pragma unroll
    for (int r = 0; r < 4; ++r) {
      int rr = row0 + wr + i * 16 + q * 4 + r;
      if (rr >= M) continue;
#pragma unroll
      for (int j = 0; j < 4; ++j) {
        int cc = col0 + wc + j * 16 + m;
        float v = acc[i][j][r];
        if (bias) v += bias[cc];
        if (do_relu) v = fmaxf(v, 0.0f);
        if (Cb) Cb[(size_t)rr * ldc + cc] = f2b(v);
        else if (rr < split) Cf[(size_t)rr * Nc + cc] = v;
        else Cf2[(size_t)(rr - split) * Nc + cc] = v;
      }
    }
  }
}

// ---------------- global_add_pool over sorted batch (bf16 in, bf16 out) ----------

__global__ __launch_bounds__(384) void pool_kernel(const short* __restrict__ NBb,
                                                   const int* __restrict__ gptr,
                                                   short* __restrict__ gcb_half,
                                                   short* __restrict__ nbb_append) {
  int g = blockIdx.x, c = threadIdx.x;
  int s = gptr[g], e = gptr[g + 1];
  float acc = 0.0f;
  for (int i = s; i < e; ++i) acc += b2f(NBb[(size_t)i * EDIM + c]);
  short bv = f2b(acc);
  gcb_half[(size_t)g * 768 + c] = bv;
  nbb_append[(size_t)g * EDIM + c] = bv;
}

// ---------------- expmap0 + proj, in-place on rows of 384 ----------------

__global__ __launch_bounds__(256) void exp_proj_kernel(float* __restrict__ y, int nrows) {
  int row = blockIdx.x * 4 + (threadIdx.x >> 6);
  int lane = threadIdx.x & 63;
  if (row >= nrows) return;
  float* p = y + (size_t)row * EDIM;
  float v[6];
  float s = 0.0f;
#pragma unroll
  for (int j = 0; j < 6; ++j) { v[j] = p[lane + j * 64]; s += v[j] * v[j]; }
  s = wave_reduce_sum(s);
  float n = fmaxf(sqrtf(s), 1e-15f);
  float th = tanhf(n);
  float f = th / n;
  float n2 = fmaxf(th, 1e-15f);
  const float maxn = 1.0f - 4e-3f;
  if (n2 > maxn) f *= maxn / n2;
#pragma unroll
  for (int j = 0; j < 6; ++j) p[lane + j * 64] = v[j] * f;
}

// ---------------- driver ----------------

extern "C" void kernel_launch(void* const* d_in, const int* in_sizes, int n_in,
                              void* d_out, int out_size, void* d_ws, size_t ws_size,
                              hipStream_t stream) {
  (void)in_sizes; (void)n_in; (void)out_size; (void)ws_size;
  const float* x   = (const float*)d_in[0];
  const float* x_s = (const float*)d_in[1];
  const int* src   = (const int*)d_in[2];
  const int* dst   = (const int*)d_in[3];
  const int* batch = (const int*)d_in[4];
  const float* Wf[3] = {(const float*)d_in[5], (const float*)d_in[6], (const float*)d_in[7]};
  const float* bf[3] = {(const float*)d_in[8], (const float*)d_in[9], (const float*)d_in[10]};
  const float* Wsb[3] = {(const float*)d_in[11], (const float*)d_in[12], (const float*)d_in[13]};
  const float* bs[3] = {(const float*)d_in[14], (const float*)d_in[15], (const float*)d_in[16]};
  const float* P1 = (const float*)d_in[17];
  const float* P2 = (const float*)d_in[18];
  const float* G1 = (const float*)d_in[19];
  const float* G2 = (const float*)d_in[20];
  float* out = (float*)d_out;

  char* w = (char*)d_ws;
  auto alloc = [&](size_t bytes) {
    char* p = w;
    w += (bytes + 255) & ~(size_t)255;
    return p;
  };
  short* Ab   = (short*)alloc((size_t)N_NODES * 128 * 2);
  short* Xa   = (short*)alloc((size_t)N_NODES * 128 * 2);   // aggregated features (pre-GEMM)
  short* NBb  = (short*)alloc((size_t)M_ALL * 384 * 2);
  short* HIDb = (short*)alloc((size_t)M_ALL * 384 * 2);
  int* cnt    = (int*)alloc((size_t)N_NODES * 4);
  int* row_ptr= (int*)alloc((size_t)(N_NODES + 1) * 4);
  int* cursor = (int*)alloc((size_t)N_NODES * 4);
  float* dinv = (float*)alloc((size_t)N_NODES * 4);
  int* col    = (int*)alloc((size_t)N_EDGES * 4);
  float* ew   = (float*)alloc((size_t)N_EDGES * 4);
  int* gptr   = (int*)alloc((size_t)(N_GRAPHS + 1) * 4);
  int* bsum   = (int*)alloc(256 * 4);
  int* boffs  = (int*)alloc(256 * 4);
  short* GCb  = (short*)alloc((size_t)N_GRAPHS * 768 * 2);
  short* GHb  = (short*)alloc((size_t)N_GRAPHS * 384 * 2);
  short* P1t  = (short*)alloc((size_t)EDIM * EDIM * 2);
  short* P2t  = (short*)alloc((size_t)EDIM * EDIM * 2);
  short* G1t  = (short*)alloc((size_t)768 * EDIM * 2);
  short* G2t  = (short*)alloc((size_t)EDIM * EDIM * 2);
  short* Wft[3], *Wst[3];
  for (int l = 0; l < 3; ++l) {
    Wft[l] = (short*)alloc((size_t)128 * 128 * 2);
    Wst[l] = (short*)alloc((size_t)128 * 128 * 2);
  }

  // ---- graph structure (shared by both branches, all layers) ----
  hipMemsetAsync(cnt, 0, (size_t)N_NODES * 4, stream);
  hist_kernel<<<(N_EDGES + 255) / 256, 256, 0, stream>>>(dst, cnt);
  gptr_kernel<<<(N_GRAPHS + 256) / 256, 256, 0, stream>>>(batch, gptr);
  scan1_kernel<<<SCAN_NB, SCAN_BS, 0, stream>>>(cnt, row_ptr, bsum);
  scan2_kernel<<<1, SCAN_BS, 0, stream>>>(bsum, boffs);
  scan3_kernel<<<SCAN_NB, SCAN_BS, 0, stream>>>(cnt, boffs, row_ptr, cursor);
  dinv_kernel<<<(N_NODES + 255) / 256, 256, 0, stream>>>(cnt, dinv);
  scatter_kernel<<<(N_EDGES + 255) / 256, 256, 0, stream>>>(src, dst, dinv, cursor, col, ew);

  {
    WcArgs wa;
    wa.seg[0] = {P1, P1t, EDIM, EDIM};
    wa.seg[1] = {P2, P2t, EDIM, EDIM};
    wa.seg[2] = {G1, G1t, 768, EDIM};
    wa.seg[3] = {G2, G2t, EDIM, EDIM};
    for (int l = 0; l < 3; ++l) {
      wa.seg[4 + l] = {Wf[l], Wft[l], 128, 128};
      wa.seg[7 + l] = {Wsb[l], Wst[l], 128, 128};
    }
    wconv_all_kernel<<<dim3((768 * EDIM + 255) / 256, 10), 256, 0, stream>>>(wa);
  }

  const size_t OUT0 = 0;
  const size_t OUT1 = (size_t)N_GRAPHS * EDIM;
  const size_t OUT2 = OUT1 + (size_t)N_GRAPHS * EDIM;
  const size_t OUT3 = OUT2 + (size_t)N_NODES * EDIM;

  const int gx_layer = (N_NODES + 127) / 128;   // 391
  const int gx_mfma  = (M_ALL + 127) / 128;     // 395
  const int gx_agg   = (N_NODES + 3) / 4;       // 12500

  auto run_branch = [&](const float* xin, short* const* Wt, const float* const* bb,
                        short* gcb_half, float* ghead_out, float* node_out) {
    logmap_kernel<<<(N_NODES + 3) / 4, 256, 0, stream>>>(xin, Ab);
    const short* cur = Ab;
    int lda = 128;
    for (int l = 0; l < 3; ++l) {
      // GCN layer, order swapped via linearity: relu(agg(X) @ W + b)
      agg_b_kernel<<<gx_agg, 256, 0, stream>>>(cur, lda, dinv, row_ptr, col, ew, Xa);
      mfma_gemm_kernel<<<dim3(gx_layer, 1), 256, 0, stream>>>(Xa, 128, Wt[l], N_NODES, 128, 128,
                                                              1, bb[l], nullptr, nullptr, 0,
                                                              NBb + l * 128, EDIM);
      cur = NBb + l * 128;
      lda = EDIM;
    }
    pool_kernel<<<N_GRAPHS, EDIM, 0, stream>>>(NBb, gptr, gcb_half,
                                               NBb + (size_t)N_NODES * EDIM);
    // fused node+graph MLP head (M = 50512 rows)
    mfma_gemm_kernel<<<dim3(gx_mfma, 3), 256, 0, stream>>>(NBb, EDIM, P1t, M_ALL, EDIM, EDIM,
                                                           1, nullptr, nullptr, nullptr, 0,
                                                           HIDb, EDIM);
    mfma_gemm_kernel<<<dim3(gx_mfma, 3), 256, 0, stream>>>(HIDb, EDIM, P2t, M_ALL, EDIM, EDIM,
                                                           0, nullptr, node_out, ghead_out,
                                                           N_NODES, nullptr, 0);
    exp_proj_kernel<<<(M_ALL + 3) / 4, 256, 0, stream>>>(ghead_out, M_ALL);
  };

  run_branch(x, Wft, bf, GCb, out + OUT1, out + OUT2);
  run_branch(x_s, Wst, bs, GCb + EDIM, out + OUT3, out + OUT3 + OUT1);

  // g head: relu(gcat @ G1) @ G2 -> out0 (bf16 MFMA, M=512)
  const int gx_g = (N_GRAPHS + 127) / 128;  // 4
  mfma_gemm_kernel<<<dim3(gx_g, 3), 256, 0, stream>>>(GCb, 768, G1t, N_GRAPHS, EDIM, 768,
                                                      1, nullptr, nullptr, nullptr, 0,
                                                      GHb, EDIM);
  mfma_gemm_kernel<<<dim3(gx_g, 3), 256, 0, stream>>>(GHb, EDIM, G2t, N_GRAPHS, EDIM, EDIM,
                                                      0, nullptr, out + OUT0, out + OUT0,
                                                      1 << 30, nullptr, 0);
  exp_proj_kernel<<<(N_GRAPHS + 3) / 4, 256, 0, stream>>>(out + OUT0, N_GRAPHS);
}

// Round 3
// 869.960 us; speedup vs baseline: 1.1433x; 1.1033x over previous
//
#include <hip/hip_runtime.h>
#include <math.h>

#define N_NODES 50000
#define N_EDGES 600000
#define N_GRAPHS 512
#define F_IN 128
#define D_HID 128
#define EDIM 384
#define M_ALL (N_NODES + N_GRAPHS)  // node rows + appended pooled graph rows

typedef __attribute__((ext_vector_type(8))) short bf16x8;
typedef __attribute__((ext_vector_type(4))) float f32x4;

static __device__ __forceinline__ float wave_reduce_sum(float s) {
#pragma unroll
  for (int off = 32; off > 0; off >>= 1) s += __shfl_xor(s, off, 64);
  return s;
}

static __device__ __forceinline__ short f2b(float f) {
  unsigned u = __float_as_uint(f);
  unsigned r = (u + 0x7FFFu + ((u >> 16) & 1u)) >> 16;
  return (short)r;
}

static __device__ __forceinline__ float b2f(short s) {
  return __uint_as_float(((unsigned)(unsigned short)s) << 16);
}

// ---------------- graph preprocessing ----------------

__global__ void hist_kernel(const int* __restrict__ dst, int* __restrict__ cnt) {
  int i = blockIdx.x * blockDim.x + threadIdx.x;
  if (i < N_EDGES) atomicAdd(&cnt[dst[i]], 1);
}

__global__ void gptr_kernel(const int* __restrict__ batch, int* __restrict__ gptr) {
  int g = blockIdx.x * blockDim.x + threadIdx.x;
  if (g > N_GRAPHS) return;
  int lo = 0, hi = N_NODES;
  while (lo < hi) { int mid = (lo + hi) >> 1; if (batch[mid] < g) lo = mid + 1; else hi = mid; }
  gptr[g] = lo;
}

// ---- 3-phase parallel exclusive scan of cnt -> row_ptr, cursor ----

#define SCAN_BS 256
#define SCAN_NB ((N_NODES + SCAN_BS - 1) / SCAN_BS)  // 196

__global__ __launch_bounds__(SCAN_BS) void scan1_kernel(const int* __restrict__ cnt,
                                                        int* __restrict__ row_ptr,
                                                        int* __restrict__ bsum) {
  __shared__ int wsum[4];
  int tid = threadIdx.x, lane = tid & 63, wid = tid >> 6;
  int idx = blockIdx.x * SCAN_BS + tid;
  int v = (idx < N_NODES) ? cnt[idx] : 0;
  int x = v;
#pragma unroll
  for (int off = 1; off < 64; off <<= 1) {
    int t = __shfl_up(x, off, 64);
    if (lane >= off) x += t;
  }
  if (lane == 63) wsum[wid] = x;
  __syncthreads();
  int pre = 0, tot = 0;
#pragma unroll
  for (int w = 0; w < 4; ++w) { int s = wsum[w]; tot += s; if (w < wid) pre += s; }
  if (idx < N_NODES) row_ptr[idx + 1] = x + pre;  // block-local inclusive
  if (tid == 0) bsum[blockIdx.x] = tot;
}

__global__ __launch_bounds__(SCAN_BS) void scan2_kernel(const int* __restrict__ bsum,
                                                        int* __restrict__ boffs) {
  __shared__ int wsum[4];
  int tid = threadIdx.x, lane = tid & 63, wid = tid >> 6;
  int v = (tid < SCAN_NB) ? bsum[tid] : 0;
  int x = v;
#pragma unroll
  for (int off = 1; off < 64; off <<= 1) {
    int t = __shfl_up(x, off, 64);
    if (lane >= off) x += t;
  }
  if (lane == 63) wsum[wid] = x;
  __syncthreads();
  int pre = 0;
#pragma unroll
  for (int w = 0; w < 4; ++w) { int s = wsum[w]; if (w < wid) pre += s; }
  if (tid < SCAN_NB) boffs[tid] = x + pre - v;  // exclusive
}

__global__ __launch_bounds__(SCAN_BS) void scan3_kernel(const int* __restrict__ cnt,
                                                        const int* __restrict__ boffs,
                                                        int* __restrict__ row_ptr,
                                                        int* __restrict__ cursor) {
  int idx = blockIdx.x * SCAN_BS + threadIdx.x;
  if (idx >= N_NODES) return;
  int val = row_ptr[idx + 1] + boffs[blockIdx.x];
  row_ptr[idx + 1] = val;
  cursor[idx] = val - cnt[idx];
  if (idx == 0) row_ptr[0] = 0;
}

__global__ void dinv_kernel(const int* __restrict__ cnt, float* __restrict__ dinv) {
  int i = blockIdx.x * blockDim.x + threadIdx.x;
  if (i < N_NODES) dinv[i] = 1.0f / sqrtf((float)(cnt[i] + 1));
}

__global__ void scatter_kernel(const int* __restrict__ src, const int* __restrict__ dst,
                               const float* __restrict__ dinv, int* __restrict__ cursor,
                               int* __restrict__ col, float* __restrict__ ew) {
  int e = blockIdx.x * blockDim.x + threadIdx.x;
  if (e >= N_EDGES) return;
  int s = src[e], d = dst[e];
  int pos = atomicAdd(&cursor[d], 1);
  col[pos] = s;
  ew[pos] = dinv[s] * dinv[d];
}

// ---------------- combined weight convert+transpose (10 matrices, 1 launch) ----

struct WcSeg { const float* W; short* Wt; int K; int Nc; };
struct WcArgs { WcSeg seg[10]; };

__global__ void wconv_all_kernel(WcArgs a) {
  int sidx = blockIdx.y;
  WcSeg s = a.seg[sidx];
  int i = blockIdx.x * blockDim.x + threadIdx.x;
  if (i >= s.K * s.Nc) return;
  int k = i / s.Nc, n = i - k * s.Nc;
  s.Wt[(size_t)n * s.K + k] = f2b(s.W[i]);
}

// ---------------- logmap0 for BOTH branches -> interleaved Ab[node][f:128|s:128] ----

__global__ __launch_bounds__(256) void logmap2_kernel(const float* __restrict__ x,
                                                      const float* __restrict__ x_s,
                                                      short* __restrict__ Ab) {
  int w = blockIdx.x * 4 + (threadIdx.x >> 6);
  int lane = threadIdx.x & 63;
  if (w >= 2 * N_NODES) return;
  int br = (w >= N_NODES) ? 1 : 0;
  int row = br ? (w - N_NODES) : w;
  const float* xr = (br ? x_s : x) + (size_t)row * F_IN;
  float2 v = *(const float2*)(xr + lane * 2);
  float s = wave_reduce_sum(v.x * v.x + v.y * v.y);
  float n = sqrtf(s);
  float nc = fmaxf(n, 1e-15f);
  float f = atanhf(fminf(nc, 0.9999999f)) / nc;
  short2 o; o.x = f2b(v.x * f); o.y = f2b(v.y * f);
  *(short2*)(Ab + (size_t)row * 256 + br * 128 + lane * 2) = o;
}

// ---------------- CSR aggregation, both branches per gather (512B rows) ----------
// Xa[node][0..255] = sum_j ew[j] * Xin[col[j]][0..255] + dinv^2 * Xin[node][0..255]
// One wave per node: 64 lanes x short4 = 512B per edge row. 4 nodes/block.

__global__ __launch_bounds__(256) void agg2_kernel(const short* __restrict__ Xin, int lda,
                                                   const float* __restrict__ dinv,
                                                   const int* __restrict__ row_ptr,
                                                   const int* __restrict__ col,
                                                   const float* __restrict__ ew,
                                                   short* __restrict__ Xa) {
  int node = blockIdx.x * 4 + (threadIdx.x >> 6);
  int lane = threadIdx.x & 63;
  if (node >= N_NODES) return;
  float di = dinv[node];
  float wsf = di * di;
  short4 sv = *(const short4*)(Xin + (size_t)node * lda + lane * 4);
  float a0 = b2f(sv.x) * wsf, a1 = b2f(sv.y) * wsf, a2 = b2f(sv.z) * wsf, a3 = b2f(sv.w) * wsf;
  int s = row_ptr[node], e = row_ptr[node + 1];
  int j = s;
  for (; j + 4 <= e; j += 4) {
    int c0 = col[j], c1 = col[j + 1], c2 = col[j + 2], c3 = col[j + 3];
    float w0 = ew[j], w1 = ew[j + 1], w2 = ew[j + 2], w3 = ew[j + 3];
    short4 v0 = *(const short4*)(Xin + (size_t)c0 * lda + lane * 4);
    short4 v1 = *(const short4*)(Xin + (size_t)c1 * lda + lane * 4);
    short4 v2 = *(const short4*)(Xin + (size_t)c2 * lda + lane * 4);
    short4 v3 = *(const short4*)(Xin + (size_t)c3 * lda + lane * 4);
    a0 += b2f(v0.x) * w0; a1 += b2f(v0.y) * w0; a2 += b2f(v0.z) * w0; a3 += b2f(v0.w) * w0;
    a0 += b2f(v1.x) * w1; a1 += b2f(v1.y) * w1; a2 += b2f(v1.z) * w1; a3 += b2f(v1.w) * w1;
    a0 += b2f(v2.x) * w2; a1 += b2f(v2.y) * w2; a2 += b2f(v2.z) * w2; a3 += b2f(v2.w) * w2;
    a0 += b2f(v3.x) * w3; a1 += b2f(v3.y) * w3; a2 += b2f(v3.z) * w3; a3 += b2f(v3.w) * w3;
  }
  for (; j < e; ++j) {
    float w0 = ew[j];
    short4 v0 = *(const short4*)(Xin + (size_t)col[j] * lda + lane * 4);
    a0 += b2f(v0.x) * w0; a1 += b2f(v0.y) * w0; a2 += b2f(v0.z) * w0; a3 += b2f(v0.w) * w0;
  }
  short4 o; o.x = f2b(a0); o.y = f2b(a1); o.z = f2b(a2); o.w = f2b(a3);
  *(short4*)(Xa + (size_t)node * 256 + lane * 4) = o;
}

// ---------------- bf16 MFMA GEMM, z-batched over 2 branches ----------------
// C[M,Nc] = A[M,K] @ Bt[Nc,K]^T per z. A row stride lda; optional K-chunk
// expansion (kexp): A column for logical k is k + (k>>7)*128 (interleaved
// [layer][branch][128] layout). Epilogue: optional bias + relu.
// Output: bf16 Cb (stride ldc) if set; else fp32 split: rows<split -> Cf
// (stride Nc), rows>=split -> Cf2 + (row-split)*Nc.

#define LDK 40  // 32 + 8 pad shorts

struct GemmZArgs {
  const short* A[2];
  const short* Bt[2];
  const float* bias[2];
  short* Cb[2];
  float* Cf[2];
  float* Cf2[2];
  int lda, ldc, M, Nc, K, kexp, do_relu, split;
};

__global__ __launch_bounds__(256) void mfma_gemmz_kernel(GemmZArgs g) {
  __shared__ __align__(16) short As[128 * LDK];
  __shared__ __align__(16) short Bs[128 * LDK];
  int z = blockIdx.z;
  const short* __restrict__ A = g.A[z];
  const short* __restrict__ Bt = g.Bt[z];
  int tid = threadIdx.x;
  int wave = tid >> 6, lane = tid & 63;
  int wr = (wave >> 1) * 64, wc = (wave & 1) * 64;
  int q = lane >> 4, m = lane & 15;
  int row0 = blockIdx.x * 128, col0 = blockIdx.y * 128;
  f32x4 acc[4][4] = {};
  for (int k0 = 0; k0 < g.K; k0 += 32) {
#pragma unroll
    for (int p = 0; p < 2; ++p) {
      int idx = p * 256 + tid;      // 0..511
      int r = idx >> 2, kc = (idx & 3) * 8;
      int gr = row0 + r;
      int kk = k0 + kc;
      int acol = g.kexp ? (kk + ((kk >> 7) << 7)) : kk;
      float4 v = make_float4(0.f, 0.f, 0.f, 0.f);
      if (gr < g.M) v = *(const float4*)(A + (size_t)gr * g.lda + acol);
      *(float4*)(As + r * LDK + kc) = v;
      float4 w = *(const float4*)(Bt + (size_t)(col0 + r) * g.K + kk);
      *(float4*)(Bs + r * LDK + kc) = w;
    }
    __syncthreads();
    bf16x8 af[4], bfr[4];
#pragma unroll
    for (int i = 0; i < 4; ++i) {
      af[i]  = *(const bf16x8*)(As + (wr + i * 16 + m) * LDK + q * 8);
      bfr[i] = *(const bf16x8*)(Bs + (wc + i * 16 + m) * LDK + q * 8);
    }
#pragma unroll
    for (int i = 0; i < 4; ++i)
#pragma unroll
      for (int j = 0; j < 4; ++j)
        acc[i][j] = __builtin_amdgcn_mfma_f32_16x16x32_bf16(af[i], bfr[j], acc[i][j], 0, 0, 0);
    __syncthreads();
  }
  const float* __restrict__ bias = g.bias[z];
  short* __restrict__ Cb = g.Cb[z];
  float* __restrict__ Cf = g.Cf[z];
  float* __restrict__ Cf2 = g.Cf2[z];
#pragma unroll
  for (int i = 0; i < 4; ++i) {
#pragma unroll
    for (int r = 0; r < 4; ++r) {
      int rr = row0 + wr + i * 16 + q * 4 + r;
      if (rr >= g.M) continue;
#pragma unroll
      for (int j = 0; j < 4; ++j) {
        int cc = col0 + wc + j * 16 + m;
        float v = acc[i][j][r];
        if (bias) v += bias[cc];
        if (g.do_relu) v = fmaxf(v, 0.0f);
        if (Cb) Cb[(size_t)rr * g.ldc + cc] = f2b(v);
        else if (rr < g.split) Cf[(size_t)rr * g.Nc + cc] = v;
        else Cf2[(size_t)(rr - g.split) * g.Nc + cc] = v;
      }
    }
  }
}

// ---------------- global_add_pool over sorted batch, interleaved layout ----------
// NB[node][l*256 + b*128 + c] -> GCb[g][b*384 + l*128 + c], append NB[(N+g)][t].

__global__ __launch_bounds__(768) void pool2_kernel(const short* __restrict__ NB,
                                                    const int* __restrict__ gptr,
                                                    short* __restrict__ GCb,
                                                    short* __restrict__ nbappend) {
  int g = blockIdx.x, t = threadIdx.x;  // t in [0,768)
  int s = gptr[g], e = gptr[g + 1];
  float acc = 0.0f;
  for (int i = s; i < e; ++i) acc += b2f(NB[(size_t)i * 768 + t]);
  short bv = f2b(acc);
  int l = t >> 8, rem = t & 255, b = rem >> 7, c = rem & 127;
  GCb[(size_t)g * 768 + b * 384 + l * 128 + c] = bv;
  nbappend[(size_t)g * 768 + t] = bv;
}

// ---------------- expmap0 + proj, in-place on rows of 384 ----------------

__global__ __launch_bounds__(256) void exp_proj_kernel(float* __restrict__ y, int nrows) {
  int row = blockIdx.x * 4 + (threadIdx.x >> 6);
  int lane = threadIdx.x & 63;
  if (row >= nrows) return;
  float* p = y + (size_t)row * EDIM;
  float v[6];
  float s = 0.0f;
#pragma unroll
  for (int j = 0; j < 6; ++j) { v[j] = p[lane + j * 64]; s += v[j] * v[j]; }
  s = wave_reduce_sum(s);
  float n = fmaxf(sqrtf(s), 1e-15f);
  float th = tanhf(n);
  float f = th / n;
  float n2 = fmaxf(th, 1e-15f);
  const float maxn = 1.0f - 4e-3f;
  if (n2 > maxn) f *= maxn / n2;
#pragma unroll
  for (int j = 0; j < 6; ++j) p[lane + j * 64] = v[j] * f;
}

// ---------------- driver ----------------

extern "C" void kernel_launch(void* const* d_in, const int* in_sizes, int n_in,
                              void* d_out, int out_size, void* d_ws, size_t ws_size,
                              hipStream_t stream) {
  (void)in_sizes; (void)n_in; (void)out_size; (void)ws_size;
  const float* x   = (const float*)d_in[0];
  const float* x_s = (const float*)d_in[1];
  const int* src   = (const int*)d_in[2];
  const int* dst   = (const int*)d_in[3];
  const int* batch = (const int*)d_in[4];
  const float* Wf[3] = {(const float*)d_in[5], (const float*)d_in[6], (const float*)d_in[7]};
  const float* bf[3] = {(const float*)d_in[8], (const float*)d_in[9], (const float*)d_in[10]};
  const float* Wsb[3] = {(const float*)d_in[11], (const float*)d_in[12], (const float*)d_in[13]};
  const float* bs[3] = {(const float*)d_in[14], (const float*)d_in[15], (const float*)d_in[16]};
  const float* P1 = (const float*)d_in[17];
  const float* P2 = (const float*)d_in[18];
  const float* G1 = (const float*)d_in[19];
  const float* G2 = (const float*)d_in[20];
  float* out = (float*)d_out;

  char* w = (char*)d_ws;
  auto alloc = [&](size_t bytes) {
    char* p = w;
    w += (bytes + 255) & ~(size_t)255;
    return p;
  };
  // HIDb (head hidden, bf16 M_ALL x 384) doubles as Ab (logmap output,
  // N x 256) -- lifetimes are disjoint (Ab: logmap->agg L0; HIDb: heads).
  short* HIDb = (short*)alloc((size_t)M_ALL * 384 * 2);
  short* Ab   = HIDb;
  short* Xa   = (short*)alloc((size_t)N_NODES * 256 * 2);   // aggregated, interleaved
  short* NB   = (short*)alloc((size_t)M_ALL * 768 * 2);     // [row][l][branch][128]
  int* cnt    = (int*)alloc((size_t)N_NODES * 4);
  int* row_ptr= (int*)alloc((size_t)(N_NODES + 1) * 4);
  int* cursor = (int*)alloc((size_t)N_NODES * 4);
  float* dinv = (float*)alloc((size_t)N_NODES * 4);
  int* col    = (int*)alloc((size_t)N_EDGES * 4);
  float* ew   = (float*)alloc((size_t)N_EDGES * 4);
  int* gptr   = (int*)alloc((size_t)(N_GRAPHS + 1) * 4);
  int* bsum   = (int*)alloc(256 * 4);
  int* boffs  = (int*)alloc(256 * 4);
  short* GCb  = (short*)alloc((size_t)N_GRAPHS * 768 * 2);
  short* GHb  = (short*)alloc((size_t)N_GRAPHS * 384 * 2);
  short* P1t  = (short*)alloc((size_t)EDIM * EDIM * 2);
  short* P2t  = (short*)alloc((size_t)EDIM * EDIM * 2);
  short* G1t  = (short*)alloc((size_t)768 * EDIM * 2);
  short* G2t  = (short*)alloc((size_t)EDIM * EDIM * 2);
  short* Wft[3], *Wst[3];
  for (int l = 0; l < 3; ++l) {
    Wft[l] = (short*)alloc((size_t)128 * 128 * 2);
    Wst[l] = (short*)alloc((size_t)128 * 128 * 2);
  }

  // ---- graph structure (shared by both branches, all layers) ----
  hipMemsetAsync(cnt, 0, (size_t)N_NODES * 4, stream);
  hist_kernel<<<(N_EDGES + 255) / 256, 256, 0, stream>>>(dst, cnt);
  gptr_kernel<<<(N_GRAPHS + 256) / 256, 256, 0, stream>>>(batch, gptr);
  scan1_kernel<<<SCAN_NB, SCAN_BS, 0, stream>>>(cnt, row_ptr, bsum);
  scan2_kernel<<<1, SCAN_BS, 0, stream>>>(bsum, boffs);
  scan3_kernel<<<SCAN_NB, SCAN_BS, 0, stream>>>(cnt, boffs, row_ptr, cursor);
  dinv_kernel<<<(N_NODES + 255) / 256, 256, 0, stream>>>(cnt, dinv);
  scatter_kernel<<<(N_EDGES + 255) / 256, 256, 0, stream>>>(src, dst, dinv, cursor, col, ew);

  {
    WcArgs wa;
    wa.seg[0] = {P1, P1t, EDIM, EDIM};
    wa.seg[1] = {P2, P2t, EDIM, EDIM};
    wa.seg[2] = {G1, G1t, 768, EDIM};
    wa.seg[3] = {G2, G2t, EDIM, EDIM};
    for (int l = 0; l < 3; ++l) {
      wa.seg[4 + l] = {Wf[l], Wft[l], 128, 128};
      wa.seg[7 + l] = {Wsb[l], Wst[l], 128, 128};
    }
    wconv_all_kernel<<<dim3((768 * EDIM + 255) / 256, 10), 256, 0, stream>>>(wa);
  }

  const size_t OUT0 = 0;
  const size_t OUT1 = (size_t)N_GRAPHS * EDIM;
  const size_t OUT2 = OUT1 + (size_t)N_GRAPHS * EDIM;
  const size_t OUT3 = OUT2 + (size_t)N_NODES * EDIM;

  const int gx_layer = (N_NODES + 127) / 128;   // 391
  const int gx_mfma  = (M_ALL + 127) / 128;     // 395
  const int gx_agg   = (N_NODES + 3) / 4;       // 12500

  // ---- logmap both branches -> interleaved Ab ----
  logmap2_kernel<<<(2 * N_NODES + 3) / 4, 256, 0, stream>>>(x, x_s, Ab);

  // ---- 3 GCN layers, both branches per launch ----
  const short* cur = Ab;
  int clda = 256;
  for (int l = 0; l < 3; ++l) {
    agg2_kernel<<<gx_agg, 256, 0, stream>>>(cur, clda, dinv, row_ptr, col, ew, Xa);
    GemmZArgs ga = {};
    ga.A[0] = Xa;        ga.A[1] = Xa + 128;
    ga.Bt[0] = Wft[l];   ga.Bt[1] = Wst[l];
    ga.bias[0] = bf[l];  ga.bias[1] = bs[l];
    ga.Cb[0] = NB + l * 256;        ga.Cb[1] = NB + l * 256 + 128;
    ga.lda = 256; ga.ldc = 768; ga.M = N_NODES; ga.Nc = 128; ga.K = 128;
    ga.kexp = 0; ga.do_relu = 1; ga.split = 0;
    mfma_gemmz_kernel<<<dim3(gx_layer, 1, 2), 256, 0, stream>>>(ga);
    cur = NB + l * 256;
    clda = 768;
  }

  // ---- pool (both branches) + append pooled rows to NB ----
  pool2_kernel<<<N_GRAPHS, 768, 0, stream>>>(NB, gptr, GCb, NB + (size_t)N_NODES * 768);

  // ---- per-branch MLP heads (shared P1/P2 weights); HIDb reused across branches ----
  float* ghead_out[2] = {out + OUT1, out + OUT3};
  float* node_out[2]  = {out + OUT2, out + OUT3 + (size_t)N_GRAPHS * EDIM};
  for (int b = 0; b < 2; ++b) {
    GemmZArgs h1 = {};
    h1.A[0] = h1.A[1] = NB + b * 128;
    h1.Bt[0] = h1.Bt[1] = P1t;
    h1.Cb[0] = h1.Cb[1] = HIDb;
    h1.lda = 768; h1.ldc = 384; h1.M = M_ALL; h1.Nc = EDIM; h1.K = EDIM;
    h1.kexp = 1; h1.do_relu = 1; h1.split = 0;
    mfma_gemmz_kernel<<<dim3(gx_mfma, 3, 1), 256, 0, stream>>>(h1);

    GemmZArgs h2 = {};
    h2.A[0] = h2.A[1] = HIDb;
    h2.Bt[0] = h2.Bt[1] = P2t;
    h2.Cf[0] = h2.Cf[1] = node_out[b];
    h2.Cf2[0] = h2.Cf2[1] = ghead_out[b];
    h2.lda = 384; h2.ldc = 0; h2.M = M_ALL; h2.Nc = EDIM; h2.K = EDIM;
    h2.kexp = 0; h2.do_relu = 0; h2.split = N_NODES;
    mfma_gemmz_kernel<<<dim3(gx_mfma, 3, 1), 256, 0, stream>>>(h2);
  }

  // ---- single expmap+proj over [g_f | n_f | g_s | n_s] (contiguous 2*M_ALL rows) ----
  exp_proj_kernel<<<(2 * M_ALL + 3) / 4, 256, 0, stream>>>(out + OUT1, 2 * M_ALL);

  // ---- g head: relu(gcat @ G1) @ G2 -> out0 (M=512) ----
  const int gx_g = (N_GRAPHS + 127) / 128;  // 4
  {
    GemmZArgs g1 = {};
    g1.A[0] = g1.A[1] = GCb;
    g1.Bt[0] = g1.Bt[1] = G1t;
    g1.Cb[0] = g1.Cb[1] = GHb;
    g1.lda = 768; g1.ldc = 384; g1.M = N_GRAPHS; g1.Nc = EDIM; g1.K = 768;
    g1.kexp = 0; g1.do_relu = 1; g1.split = 0;
    mfma_gemmz_kernel<<<dim3(gx_g, 3, 1), 256, 0, stream>>>(g1);

    GemmZArgs g2 = {};
    g2.A[0] = g2.A[1] = GHb;
    g2.Bt[0] = g2.Bt[1] = G2t;
    g2.Cf[0] = g2.Cf[1] = out + OUT0;
    g2.Cf2[0] = g2.Cf2[1] = out + OUT0;
    g2.lda = 384; g2.ldc = 0; g2.M = N_GRAPHS; g2.Nc = EDIM; g2.K = EDIM;
    g2.kexp = 0; g2.do_relu = 0; g2.split = 1 << 30;
    mfma_gemmz_kernel<<<dim3(gx_g, 3, 1), 256, 0, stream>>>(g2);
  }
  exp_proj_kernel<<<(N_GRAPHS + 3) / 4, 256, 0, stream>>>(out + OUT0, N_GRAPHS);
}

// Round 4
// 844.802 us; speedup vs baseline: 1.1773x; 1.0298x over previous
//
#include <hip/hip_runtime.h>
#include <math.h>

#define N_NODES 50000
#define N_EDGES 600000
#define N_GRAPHS 512
#define F_IN 128
#define D_HID 128
#define EDIM 384
#define M_ALL (N_NODES + N_GRAPHS)  // node rows + appended pooled graph rows

typedef __attribute__((ext_vector_type(8))) short bf16x8;
typedef __attribute__((ext_vector_type(4))) float f32x4;

static __device__ __forceinline__ float wave_reduce_sum(float s) {
#pragma unroll
  for (int off = 32; off > 0; off >>= 1) s += __shfl_xor(s, off, 64);
  return s;
}

static __device__ __forceinline__ int wave_reduce_sum_i(int s) {
#pragma unroll
  for (int off = 32; off > 0; off >>= 1) s += __shfl_xor(s, off, 64);
  return s;
}

static __device__ __forceinline__ short f2b(float f) {
  unsigned u = __float_as_uint(f);
  unsigned r = (u + 0x7FFFu + ((u >> 16) & 1u)) >> 16;
  return (short)r;
}

static __device__ __forceinline__ float b2f(short s) {
  return __uint_as_float(((unsigned)(unsigned short)s) << 16);
}

// ---------------- graph preprocessing ----------------

#define SCAN_BS 256
#define SCAN_NB ((N_NODES + SCAN_BS - 1) / SCAN_BS)  // 196

// zero cnt + compute gptr (binary search over sorted batch), one launch
__global__ __launch_bounds__(SCAN_BS) void init_kernel(const int* __restrict__ batch,
                                                       int* __restrict__ cnt,
                                                       int* __restrict__ gptr) {
  int i = blockIdx.x * SCAN_BS + threadIdx.x;
  if (i < N_NODES) cnt[i] = 0;
  if (i <= N_GRAPHS) {
    int lo = 0, hi = N_NODES;
    while (lo < hi) { int mid = (lo + hi) >> 1; if (batch[mid] < i) lo = mid + 1; else hi = mid; }
    gptr[i] = lo;
  }
}

__global__ void hist_kernel(const int* __restrict__ dst, int* __restrict__ cnt) {
  int i = blockIdx.x * blockDim.x + threadIdx.x;
  if (i < N_EDGES) atomicAdd(&cnt[dst[i]], 1);
}

__global__ __launch_bounds__(SCAN_BS) void scan1_kernel(const int* __restrict__ cnt,
                                                        int* __restrict__ row_ptr,
                                                        int* __restrict__ bsum) {
  __shared__ int wsum[4];
  int tid = threadIdx.x, lane = tid & 63, wid = tid >> 6;
  int idx = blockIdx.x * SCAN_BS + tid;
  int v = (idx < N_NODES) ? cnt[idx] : 0;
  int x = v;
#pragma unroll
  for (int off = 1; off < 64; off <<= 1) {
    int t = __shfl_up(x, off, 64);
    if (lane >= off) x += t;
  }
  if (lane == 63) wsum[wid] = x;
  __syncthreads();
  int pre = 0, tot = 0;
#pragma unroll
  for (int w = 0; w < 4; ++w) { int s = wsum[w]; tot += s; if (w < wid) pre += s; }
  if (idx < N_NODES) row_ptr[idx + 1] = x + pre;  // block-local inclusive
  if (tid == 0) bsum[blockIdx.x] = tot;
}

// scan3 with fused scan2 (local re-reduction of bsum prefix) + fused dinv
__global__ __launch_bounds__(SCAN_BS) void scan3_kernel(const int* __restrict__ cnt,
                                                        const int* __restrict__ bsum,
                                                        int* __restrict__ row_ptr,
                                                        int* __restrict__ cursor,
                                                        float* __restrict__ dinv) {
  __shared__ int ws[4];
  int tid = threadIdx.x, lane = tid & 63, wid = tid >> 6;
  int v = 0;
  if (tid < SCAN_NB && tid < blockIdx.x) v = bsum[tid];
  v = wave_reduce_sum_i(v);
  if (lane == 0) ws[wid] = v;
  __syncthreads();
  int boff = ws[0] + ws[1] + ws[2] + ws[3];
  int idx = blockIdx.x * SCAN_BS + tid;
  if (idx >= N_NODES) return;
  int val = row_ptr[idx + 1] + boff;
  row_ptr[idx + 1] = val;
  int c = cnt[idx];
  cursor[idx] = val - c;
  dinv[idx] = 1.0f / sqrtf((float)(c + 1));
  if (idx == 0) row_ptr[0] = 0;
}

__global__ void scatter_kernel(const int* __restrict__ src, const int* __restrict__ dst,
                               const float* __restrict__ dinv, int* __restrict__ cursor,
                               int* __restrict__ col, float* __restrict__ ew) {
  int e = blockIdx.x * blockDim.x + threadIdx.x;
  if (e >= N_EDGES) return;
  int s = src[e], d = dst[e];
  int pos = atomicAdd(&cursor[d], 1);
  col[pos] = s;
  ew[pos] = dinv[s] * dinv[d];
}

// ---------------- combined weight convert+transpose (10 matrices, 1 launch) ----

struct WcSeg { const float* W; short* Wt; int K; int Nc; };
struct WcArgs { WcSeg seg[10]; };

__global__ void wconv_all_kernel(WcArgs a) {
  int sidx = blockIdx.y;
  WcSeg s = a.seg[sidx];
  int i = blockIdx.x * blockDim.x + threadIdx.x;
  if (i >= s.K * s.Nc) return;
  int k = i / s.Nc, n = i - k * s.Nc;
  s.Wt[(size_t)n * s.K + k] = f2b(s.W[i]);
}

// ---------------- logmap0 for BOTH branches -> interleaved Ab[node][f:128|s:128] ----

__global__ __launch_bounds__(256) void logmap2_kernel(const float* __restrict__ x,
                                                      const float* __restrict__ x_s,
                                                      short* __restrict__ Ab) {
  int w = blockIdx.x * 4 + (threadIdx.x >> 6);
  int lane = threadIdx.x & 63;
  if (w >= 2 * N_NODES) return;
  int br = (w >= N_NODES) ? 1 : 0;
  int row = br ? (w - N_NODES) : w;
  const float* xr = (br ? x_s : x) + (size_t)row * F_IN;
  float2 v = *(const float2*)(xr + lane * 2);
  float s = wave_reduce_sum(v.x * v.x + v.y * v.y);
  float n = sqrtf(s);
  float nc = fmaxf(n, 1e-15f);
  float f = atanhf(fminf(nc, 0.9999999f)) / nc;
  short2 o; o.x = f2b(v.x * f); o.y = f2b(v.y * f);
  *(short2*)(Ab + (size_t)row * 256 + br * 128 + lane * 2) = o;
}

// ---------------- CSR aggregation, both branches per gather (512B rows) ----------

__global__ __launch_bounds__(256) void agg2_kernel(const short* __restrict__ Xin, int lda,
                                                   const float* __restrict__ dinv,
                                                   const int* __restrict__ row_ptr,
                                                   const int* __restrict__ col,
                                                   const float* __restrict__ ew,
                                                   short* __restrict__ Xa) {
  int node = blockIdx.x * 4 + (threadIdx.x >> 6);
  int lane = threadIdx.x & 63;
  if (node >= N_NODES) return;
  float di = dinv[node];
  float wsf = di * di;
  short4 sv = *(const short4*)(Xin + (size_t)node * lda + lane * 4);
  float a0 = b2f(sv.x) * wsf, a1 = b2f(sv.y) * wsf, a2 = b2f(sv.z) * wsf, a3 = b2f(sv.w) * wsf;
  int s = row_ptr[node], e = row_ptr[node + 1];
  int j = s;
  for (; j + 4 <= e; j += 4) {
    int c0 = col[j], c1 = col[j + 1], c2 = col[j + 2], c3 = col[j + 3];
    float w0 = ew[j], w1 = ew[j + 1], w2 = ew[j + 2], w3 = ew[j + 3];
    short4 v0 = *(const short4*)(Xin + (size_t)c0 * lda + lane * 4);
    short4 v1 = *(const short4*)(Xin + (size_t)c1 * lda + lane * 4);
    short4 v2 = *(const short4*)(Xin + (size_t)c2 * lda + lane * 4);
    short4 v3 = *(const short4*)(Xin + (size_t)c3 * lda + lane * 4);
    a0 += b2f(v0.x) * w0; a1 += b2f(v0.y) * w0; a2 += b2f(v0.z) * w0; a3 += b2f(v0.w) * w0;
    a0 += b2f(v1.x) * w1; a1 += b2f(v1.y) * w1; a2 += b2f(v1.z) * w1; a3 += b2f(v1.w) * w1;
    a0 += b2f(v2.x) * w2; a1 += b2f(v2.y) * w2; a2 += b2f(v2.z) * w2; a3 += b2f(v2.w) * w2;
    a0 += b2f(v3.x) * w3; a1 += b2f(v3.y) * w3; a2 += b2f(v3.z) * w3; a3 += b2f(v3.w) * w3;
  }
  for (; j < e; ++j) {
    float w0 = ew[j];
    short4 v0 = *(const short4*)(Xin + (size_t)col[j] * lda + lane * 4);
    a0 += b2f(v0.x) * w0; a1 += b2f(v0.y) * w0; a2 += b2f(v0.z) * w0; a3 += b2f(v0.w) * w0;
  }
  short4 o; o.x = f2b(a0); o.y = f2b(a1); o.z = f2b(a2); o.w = f2b(a3);
  *(short4*)(Xa + (size_t)node * 256 + lane * 4) = o;
}

// ---------------- bf16 MFMA GEMM, z-batched (2 independent problems) ----------

#define LDK 40  // 32 + 8 pad shorts

struct GemmZArgs {
  const short* A[2];
  const short* Bt[2];
  const float* bias[2];
  short* Cb[2];
  float* Cf[2];
  float* Cf2[2];
  int lda, ldc, M, Nc, K, kexp, do_relu, split;
};

__global__ __launch_bounds__(256) void mfma_gemmz_kernel(GemmZArgs g) {
  __shared__ __align__(16) short As[128 * LDK];
  __shared__ __align__(16) short Bs[128 * LDK];
  int z = blockIdx.z;
  const short* __restrict__ A = g.A[z];
  const short* __restrict__ Bt = g.Bt[z];
  int tid = threadIdx.x;
  int wave = tid >> 6, lane = tid & 63;
  int wr = (wave >> 1) * 64, wc = (wave & 1) * 64;
  int q = lane >> 4, m = lane & 15;
  int row0 = blockIdx.x * 128, col0 = blockIdx.y * 128;
  f32x4 acc[4][4] = {};
  for (int k0 = 0; k0 < g.K; k0 += 32) {
#pragma unroll
    for (int p = 0; p < 2; ++p) {
      int idx = p * 256 + tid;      // 0..511
      int r = idx >> 2, kc = (idx & 3) * 8;
      int gr = row0 + r;
      int kk = k0 + kc;
      int acol = g.kexp ? (kk + ((kk >> 7) << 7)) : kk;
      float4 v = make_float4(0.f, 0.f, 0.f, 0.f);
      if (gr < g.M) v = *(const float4*)(A + (size_t)gr * g.lda + acol);
      *(float4*)(As + r * LDK + kc) = v;
      float4 w = *(const float4*)(Bt + (size_t)(col0 + r) * g.K + kk);
      *(float4*)(Bs + r * LDK + kc) = w;
    }
    __syncthreads();
    bf16x8 af[4], bfr[4];
#pragma unroll
    for (int i = 0; i < 4; ++i) {
      af[i]  = *(const bf16x8*)(As + (wr + i * 16 + m) * LDK + q * 8);
      bfr[i] = *(const bf16x8*)(Bs + (wc + i * 16 + m) * LDK + q * 8);
    }
#pragma unroll
    for (int i = 0; i < 4; ++i)
#pragma unroll
      for (int j = 0; j < 4; ++j)
        acc[i][j] = __builtin_amdgcn_mfma_f32_16x16x32_bf16(af[i], bfr[j], acc[i][j], 0, 0, 0);
    __syncthreads();
  }
  const float* __restrict__ bias = g.bias[z];
  short* __restrict__ Cb = g.Cb[z];
  float* __restrict__ Cf = g.Cf[z];
  float* __restrict__ Cf2 = g.Cf2[z];
#pragma unroll
  for (int i = 0; i < 4; ++i) {
#pragma unroll
    for (int r = 0; r < 4; ++r) {
      int rr = row0 + wr + i * 16 + q * 4 + r;
      if (rr >= g.M) continue;
#pragma unroll
      for (int j = 0; j < 4; ++j) {
        int cc = col0 + wc + j * 16 + m;
        float v = acc[i][j][r];
        if (bias) v += bias[cc];
        if (g.do_relu) v = fmaxf(v, 0.0f);
        if (Cb) Cb[(size_t)rr * g.ldc + cc] = f2b(v);
        else if (rr < g.split) Cf[(size_t)rr * g.Nc + cc] = v;
        else Cf2[(size_t)(rr - g.split) * g.Nc + cc] = v;
      }
    }
  }
}

// ---------------- global_add_pool over sorted batch, interleaved layout ----------

__global__ __launch_bounds__(768) void pool2_kernel(const short* __restrict__ NB,
                                                    const int* __restrict__ gptr,
                                                    short* __restrict__ GCb,
                                                    short* __restrict__ nbappend) {
  int g = blockIdx.x, t = threadIdx.x;  // t in [0,768)
  int s = gptr[g], e = gptr[g + 1];
  float acc = 0.0f;
  for (int i = s; i < e; ++i) acc += b2f(NB[(size_t)i * 768 + t]);
  short bv = f2b(acc);
  int l = t >> 8, rem = t & 255, b = rem >> 7, c = rem & 127;
  GCb[(size_t)g * 768 + b * 384 + l * 128 + c] = bv;
  nbappend[(size_t)g * 768 + t] = bv;
}

// ---------------- expmap0 + proj, in-place on rows of 384 ----------------

__global__ __launch_bounds__(256) void exp_proj_kernel(float* __restrict__ y, int nrows) {
  int row = blockIdx.x * 4 + (threadIdx.x >> 6);
  int lane = threadIdx.x & 63;
  if (row >= nrows) return;
  float* p = y + (size_t)row * EDIM;
  float v[6];
  float s = 0.0f;
#pragma unroll
  for (int j = 0; j < 6; ++j) { v[j] = p[lane + j * 64]; s += v[j] * v[j]; }
  s = wave_reduce_sum(s);
  float n = fmaxf(sqrtf(s), 1e-15f);
  float th = tanhf(n);
  float f = th / n;
  float n2 = fmaxf(th, 1e-15f);
  const float maxn = 1.0f - 4e-3f;
  if (n2 > maxn) f *= maxn / n2;
#pragma unroll
  for (int j = 0; j < 6; ++j) p[lane + j * 64] = v[j] * f;
}

// ---------------- driver ----------------

extern "C" void kernel_launch(void* const* d_in, const int* in_sizes, int n_in,
                              void* d_out, int out_size, void* d_ws, size_t ws_size,
                              hipStream_t stream) {
  (void)in_sizes; (void)n_in; (void)out_size; (void)ws_size;
  const float* x   = (const float*)d_in[0];
  const float* x_s = (const float*)d_in[1];
  const int* src   = (const int*)d_in[2];
  const int* dst   = (const int*)d_in[3];
  const int* batch = (const int*)d_in[4];
  const float* Wf[3] = {(const float*)d_in[5], (const float*)d_in[6], (const float*)d_in[7]};
  const float* bf[3] = {(const float*)d_in[8], (const float*)d_in[9], (const float*)d_in[10]};
  const float* Wsb[3] = {(const float*)d_in[11], (const float*)d_in[12], (const float*)d_in[13]};
  const float* bs[3] = {(const float*)d_in[14], (const float*)d_in[15], (const float*)d_in[16]};
  const float* P1 = (const float*)d_in[17];
  const float* P2 = (const float*)d_in[18];
  const float* G1 = (const float*)d_in[19];
  const float* G2 = (const float*)d_in[20];
  float* out = (float*)d_out;

  char* w = (char*)d_ws;
  auto alloc = [&](size_t bytes) {
    char* p = w;
    w += (bytes + 255) & ~(size_t)255;
    return p;
  };
  // HIDb2 (head hidden, bf16, per-branch: 2 x M_ALL x 384) doubles as Ab
  // (logmap output, N x 256) -- lifetimes disjoint (Ab: logmap->agg L0).
  short* HIDb2 = (short*)alloc((size_t)2 * M_ALL * 384 * 2);
  short* Ab    = HIDb2;
  short* Xa    = (short*)alloc((size_t)N_NODES * 256 * 2);   // aggregated, interleaved
  short* NB    = (short*)alloc((size_t)M_ALL * 768 * 2);     // [row][l][branch][128]
  int* cnt     = (int*)alloc((size_t)N_NODES * 4);
  int* row_ptr = (int*)alloc((size_t)(N_NODES + 1) * 4);
  int* cursor  = (int*)alloc((size_t)N_NODES * 4);
  float* dinv  = (float*)alloc((size_t)N_NODES * 4);
  int* col     = (int*)alloc((size_t)N_EDGES * 4);
  float* ew    = (float*)alloc((size_t)N_EDGES * 4);
  int* gptr    = (int*)alloc((size_t)(N_GRAPHS + 1) * 4);
  int* bsum    = (int*)alloc(256 * 4);
  short* GCb   = (short*)alloc((size_t)N_GRAPHS * 768 * 2);
  short* GHb   = (short*)alloc((size_t)N_GRAPHS * 384 * 2);
  short* P1t   = (short*)alloc((size_t)EDIM * EDIM * 2);
  short* P2t   = (short*)alloc((size_t)EDIM * EDIM * 2);
  short* G1t   = (short*)alloc((size_t)768 * EDIM * 2);
  short* G2t   = (short*)alloc((size_t)EDIM * EDIM * 2);
  short* Wft[3], *Wst[3];
  for (int l = 0; l < 3; ++l) {
    Wft[l] = (short*)alloc((size_t)128 * 128 * 2);
    Wst[l] = (short*)alloc((size_t)128 * 128 * 2);
  }

  // ---- weight convert (independent of graph) ----
  {
    WcArgs wa;
    wa.seg[0] = {P1, P1t, EDIM, EDIM};
    wa.seg[1] = {P2, P2t, EDIM, EDIM};
    wa.seg[2] = {G1, G1t, 768, EDIM};
    wa.seg[3] = {G2, G2t, EDIM, EDIM};
    for (int l = 0; l < 3; ++l) {
      wa.seg[4 + l] = {Wf[l], Wft[l], 128, 128};
      wa.seg[7 + l] = {Wsb[l], Wst[l], 128, 128};
    }
    wconv_all_kernel<<<dim3((768 * EDIM + 255) / 256, 10), 256, 0, stream>>>(wa);
  }

  // ---- graph structure: 5 launches (init, hist, scan1, scan3(+scan2+dinv), scatter) ----
  init_kernel<<<SCAN_NB, SCAN_BS, 0, stream>>>(batch, cnt, gptr);
  hist_kernel<<<(N_EDGES + 255) / 256, 256, 0, stream>>>(dst, cnt);
  scan1_kernel<<<SCAN_NB, SCAN_BS, 0, stream>>>(cnt, row_ptr, bsum);
  scan3_kernel<<<SCAN_NB, SCAN_BS, 0, stream>>>(cnt, bsum, row_ptr, cursor, dinv);
  scatter_kernel<<<(N_EDGES + 255) / 256, 256, 0, stream>>>(src, dst, dinv, cursor, col, ew);

  const size_t OUT0 = 0;
  const size_t OUT1 = (size_t)N_GRAPHS * EDIM;
  const size_t OUT2 = OUT1 + (size_t)N_GRAPHS * EDIM;
  const size_t OUT3 = OUT2 + (size_t)N_NODES * EDIM;

  const int gx_layer = (N_NODES + 127) / 128;   // 391
  const int gx_mfma  = (M_ALL + 127) / 128;     // 395
  const int gx_agg   = (N_NODES + 3) / 4;       // 12500

  // ---- logmap both branches -> interleaved Ab ----
  logmap2_kernel<<<(2 * N_NODES + 3) / 4, 256, 0, stream>>>(x, x_s, Ab);

  // ---- 3 GCN layers, both branches per launch ----
  const short* cur = Ab;
  int clda = 256;
  for (int l = 0; l < 3; ++l) {
    agg2_kernel<<<gx_agg, 256, 0, stream>>>(cur, clda, dinv, row_ptr, col, ew, Xa);
    GemmZArgs ga = {};
    ga.A[0] = Xa;        ga.A[1] = Xa + 128;
    ga.Bt[0] = Wft[l];   ga.Bt[1] = Wst[l];
    ga.bias[0] = bf[l];  ga.bias[1] = bs[l];
    ga.Cb[0] = NB + l * 256;        ga.Cb[1] = NB + l * 256 + 128;
    ga.lda = 256; ga.ldc = 768; ga.M = N_NODES; ga.Nc = 128; ga.K = 128;
    ga.kexp = 0; ga.do_relu = 1; ga.split = 0;
    mfma_gemmz_kernel<<<dim3(gx_layer, 1, 2), 256, 0, stream>>>(ga);
    cur = NB + l * 256;
    clda = 768;
  }

  // ---- pool (both branches) + append pooled rows to NB ----
  pool2_kernel<<<N_GRAPHS, 768, 0, stream>>>(NB, gptr, GCb, NB + (size_t)N_NODES * 768);

  // ---- g head first (so one exp_proj covers everything): relu(gcat@G1)@G2 -> out0 ----
  const int gx_g = (N_GRAPHS + 127) / 128;  // 4
  {
    GemmZArgs g1 = {};
    g1.A[0] = g1.A[1] = GCb;
    g1.Bt[0] = g1.Bt[1] = G1t;
    g1.Cb[0] = g1.Cb[1] = GHb;
    g1.lda = 768; g1.ldc = 384; g1.M = N_GRAPHS; g1.Nc = EDIM; g1.K = 768;
    g1.kexp = 0; g1.do_relu = 1; g1.split = 0;
    mfma_gemmz_kernel<<<dim3(gx_g, 3, 1), 256, 0, stream>>>(g1);

    GemmZArgs g2 = {};
    g2.A[0] = g2.A[1] = GHb;
    g2.Bt[0] = g2.Bt[1] = G2t;
    g2.Cf[0] = g2.Cf[1] = out + OUT0;
    g2.Cf2[0] = g2.Cf2[1] = out + OUT0;
    g2.lda = 384; g2.ldc = 0; g2.M = N_GRAPHS; g2.Nc = EDIM; g2.K = EDIM;
    g2.kexp = 0; g2.do_relu = 0; g2.split = 1 << 30;
    mfma_gemmz_kernel<<<dim3(gx_g, 3, 1), 256, 0, stream>>>(g2);
  }

  // ---- node+graph MLP heads, both branches z-batched (2 launches total) ----
  float* ghead_out[2] = {out + OUT1, out + OUT3};
  float* node_out[2]  = {out + OUT2, out + OUT3 + (size_t)N_GRAPHS * EDIM};
  {
    GemmZArgs h1 = {};
    h1.A[0] = NB;                 h1.A[1] = NB + 128;
    h1.Bt[0] = h1.Bt[1] = P1t;
    h1.Cb[0] = HIDb2;             h1.Cb[1] = HIDb2 + (size_t)M_ALL * 384;
    h1.lda = 768; h1.ldc = 384; h1.M = M_ALL; h1.Nc = EDIM; h1.K = EDIM;
    h1.kexp = 1; h1.do_relu = 1; h1.split = 0;
    mfma_gemmz_kernel<<<dim3(gx_mfma, 3, 2), 256, 0, stream>>>(h1);

    GemmZArgs h2 = {};
    h2.A[0] = HIDb2;              h2.A[1] = HIDb2 + (size_t)M_ALL * 384;
    h2.Bt[0] = h2.Bt[1] = P2t;
    h2.Cf[0] = node_out[0];       h2.Cf[1] = node_out[1];
    h2.Cf2[0] = ghead_out[0];     h2.Cf2[1] = ghead_out[1];
    h2.lda = 384; h2.ldc = 0; h2.M = M_ALL; h2.Nc = EDIM; h2.K = EDIM;
    h2.kexp = 0; h2.do_relu = 0; h2.split = N_NODES;
    mfma_gemmz_kernel<<<dim3(gx_mfma, 3, 2), 256, 0, stream>>>(h2);
  }

  // ---- single expmap+proj over [g | g_f | n_f | g_s | n_s] (contiguous) ----
  const int nrows_exp = N_GRAPHS + 2 * M_ALL;  // 101536
  exp_proj_kernel<<<(nrows_exp + 3) / 4, 256, 0, stream>>>(out + OUT0, nrows_exp);
}

// Round 5
// 770.518 us; speedup vs baseline: 1.2908x; 1.0964x over previous
//
#include <hip/hip_runtime.h>
#include <math.h>

#define N_NODES 50000
#define N_EDGES 600000
#define N_GRAPHS 512
#define F_IN 128
#define D_HID 128
#define EDIM 384
#define M_ALL (N_NODES + N_GRAPHS)  // node rows + appended pooled graph rows

typedef __attribute__((ext_vector_type(8))) short bf16x8;
typedef __attribute__((ext_vector_type(4))) float f32x4;

static __device__ __forceinline__ float wave_reduce_sum(float s) {
#pragma unroll
  for (int off = 32; off > 0; off >>= 1) s += __shfl_xor(s, off, 64);
  return s;
}

static __device__ __forceinline__ int wave_reduce_sum_i(int s) {
#pragma unroll
  for (int off = 32; off > 0; off >>= 1) s += __shfl_xor(s, off, 64);
  return s;
}

static __device__ __forceinline__ short f2b(float f) {
  unsigned u = __float_as_uint(f);
  unsigned r = (u + 0x7FFFu + ((u >> 16) & 1u)) >> 16;
  return (short)r;
}

static __device__ __forceinline__ float b2f(short s) {
  return __uint_as_float(((unsigned)(unsigned short)s) << 16);
}

// ---------------- graph preprocessing ----------------

#define SCAN_BS 256
#define SCAN_NB ((N_NODES + SCAN_BS - 1) / SCAN_BS)  // 196

// zero cnt + compute gptr (binary search over sorted batch), one launch
__global__ __launch_bounds__(SCAN_BS) void init_kernel(const int* __restrict__ batch,
                                                       int* __restrict__ cnt,
                                                       int* __restrict__ gptr) {
  int i = blockIdx.x * SCAN_BS + threadIdx.x;
  if (i < N_NODES) cnt[i] = 0;
  if (i <= N_GRAPHS) {
    int lo = 0, hi = N_NODES;
    while (lo < hi) { int mid = (lo + hi) >> 1; if (batch[mid] < i) lo = mid + 1; else hi = mid; }
    gptr[i] = lo;
  }
}

__global__ void hist_kernel(const int* __restrict__ dst, int* __restrict__ cnt) {
  int i = blockIdx.x * blockDim.x + threadIdx.x;
  if (i < N_EDGES) atomicAdd(&cnt[dst[i]], 1);
}

__global__ __launch_bounds__(SCAN_BS) void scan1_kernel(const int* __restrict__ cnt,
                                                        int* __restrict__ row_ptr,
                                                        int* __restrict__ bsum) {
  __shared__ int wsum[4];
  int tid = threadIdx.x, lane = tid & 63, wid = tid >> 6;
  int idx = blockIdx.x * SCAN_BS + tid;
  int v = (idx < N_NODES) ? cnt[idx] : 0;
  int x = v;
#pragma unroll
  for (int off = 1; off < 64; off <<= 1) {
    int t = __shfl_up(x, off, 64);
    if (lane >= off) x += t;
  }
  if (lane == 63) wsum[wid] = x;
  __syncthreads();
  int pre = 0, tot = 0;
#pragma unroll
  for (int w = 0; w < 4; ++w) { int s = wsum[w]; tot += s; if (w < wid) pre += s; }
  if (idx < N_NODES) row_ptr[idx + 1] = x + pre;  // block-local inclusive
  if (tid == 0) bsum[blockIdx.x] = tot;
}

// scan3 with fused scan2 (local re-reduction of bsum prefix) + fused dinv
__global__ __launch_bounds__(SCAN_BS) void scan3_kernel(const int* __restrict__ cnt,
                                                        const int* __restrict__ bsum,
                                                        int* __restrict__ row_ptr,
                                                        int* __restrict__ cursor,
                                                        float* __restrict__ dinv) {
  __shared__ int ws[4];
  int tid = threadIdx.x, lane = tid & 63, wid = tid >> 6;
  int v = 0;
  if (tid < SCAN_NB && tid < blockIdx.x) v = bsum[tid];
  v = wave_reduce_sum_i(v);
  if (lane == 0) ws[wid] = v;
  __syncthreads();
  int boff = ws[0] + ws[1] + ws[2] + ws[3];
  int idx = blockIdx.x * SCAN_BS + tid;
  if (idx >= N_NODES) return;
  int val = row_ptr[idx + 1] + boff;
  row_ptr[idx + 1] = val;
  int c = cnt[idx];
  cursor[idx] = val - c;
  dinv[idx] = 1.0f / sqrtf((float)(c + 1));
  if (idx == 0) row_ptr[0] = 0;
}

__global__ void scatter_kernel(const int* __restrict__ src, const int* __restrict__ dst,
                               const float* __restrict__ dinv, int* __restrict__ cursor,
                               int* __restrict__ col, float* __restrict__ ew) {
  int e = blockIdx.x * blockDim.x + threadIdx.x;
  if (e >= N_EDGES) return;
  int s = src[e], d = dst[e];
  int pos = atomicAdd(&cursor[d], 1);
  col[pos] = s;
  ew[pos] = dinv[s] * dinv[d];
}

// ---------------- combined weight convert+transpose (10 matrices, 1 launch) ----

struct WcSeg { const float* W; short* Wt; int K; int Nc; };
struct WcArgs { WcSeg seg[10]; };

__global__ void wconv_all_kernel(WcArgs a) {
  int sidx = blockIdx.y;
  WcSeg s = a.seg[sidx];
  int i = blockIdx.x * blockDim.x + threadIdx.x;
  if (i >= s.K * s.Nc) return;
  int k = i / s.Nc, n = i - k * s.Nc;
  s.Wt[(size_t)n * s.K + k] = f2b(s.W[i]);
}

// ---------------- logmap0 for BOTH branches -> interleaved Ab[node][f:128|s:128] ----

__global__ __launch_bounds__(256) void logmap2_kernel(const float* __restrict__ x,
                                                      const float* __restrict__ x_s,
                                                      short* __restrict__ Ab) {
  int w = blockIdx.x * 4 + (threadIdx.x >> 6);
  int lane = threadIdx.x & 63;
  if (w >= 2 * N_NODES) return;
  int br = (w >= N_NODES) ? 1 : 0;
  int row = br ? (w - N_NODES) : w;
  const float* xr = (br ? x_s : x) + (size_t)row * F_IN;
  float2 v = *(const float2*)(xr + lane * 2);
  float s = wave_reduce_sum(v.x * v.x + v.y * v.y);
  float n = sqrtf(s);
  float nc = fmaxf(n, 1e-15f);
  float f = atanhf(fminf(nc, 0.9999999f)) / nc;
  short2 o; o.x = f2b(v.x * f); o.y = f2b(v.y * f);
  *(short2*)(Ab + (size_t)row * 256 + br * 128 + lane * 2) = o;
}

// ---------------- CSR aggregation, both branches per gather (512B rows) ----------

__global__ __launch_bounds__(256) void agg2_kernel(const short* __restrict__ Xin, int lda,
                                                   const float* __restrict__ dinv,
                                                   const int* __restrict__ row_ptr,
                                                   const int* __restrict__ col,
                                                   const float* __restrict__ ew,
                                                   short* __restrict__ Xa) {
  int node = blockIdx.x * 4 + (threadIdx.x >> 6);
  int lane = threadIdx.x & 63;
  if (node >= N_NODES) return;
  float di = dinv[node];
  float wsf = di * di;
  short4 sv = *(const short4*)(Xin + (size_t)node * lda + lane * 4);
  float a0 = b2f(sv.x) * wsf, a1 = b2f(sv.y) * wsf, a2 = b2f(sv.z) * wsf, a3 = b2f(sv.w) * wsf;
  int s = row_ptr[node], e = row_ptr[node + 1];
  int j = s;
  for (; j + 4 <= e; j += 4) {
    int c0 = col[j], c1 = col[j + 1], c2 = col[j + 2], c3 = col[j + 3];
    float w0 = ew[j], w1 = ew[j + 1], w2 = ew[j + 2], w3 = ew[j + 3];
    short4 v0 = *(const short4*)(Xin + (size_t)c0 * lda + lane * 4);
    short4 v1 = *(const short4*)(Xin + (size_t)c1 * lda + lane * 4);
    short4 v2 = *(const short4*)(Xin + (size_t)c2 * lda + lane * 4);
    short4 v3 = *(const short4*)(Xin + (size_t)c3 * lda + lane * 4);
    a0 += b2f(v0.x) * w0; a1 += b2f(v0.y) * w0; a2 += b2f(v0.z) * w0; a3 += b2f(v0.w) * w0;
    a0 += b2f(v1.x) * w1; a1 += b2f(v1.y) * w1; a2 += b2f(v1.z) * w1; a3 += b2f(v1.w) * w1;
    a0 += b2f(v2.x) * w2; a1 += b2f(v2.y) * w2; a2 += b2f(v2.z) * w2; a3 += b2f(v2.w) * w2;
    a0 += b2f(v3.x) * w3; a1 += b2f(v3.y) * w3; a2 += b2f(v3.z) * w3; a3 += b2f(v3.w) * w3;
  }
  for (; j < e; ++j) {
    float w0 = ew[j];
    short4 v0 = *(const short4*)(Xin + (size_t)col[j] * lda + lane * 4);
    a0 += b2f(v0.x) * w0; a1 += b2f(v0.y) * w0; a2 += b2f(v0.z) * w0; a3 += b2f(v0.w) * w0;
  }
  short4 o; o.x = f2b(a0); o.y = f2b(a1); o.z = f2b(a2); o.w = f2b(a3);
  *(short4*)(Xa + (size_t)node * 256 + lane * 4) = o;
}

// ---------------- bf16 MFMA GEMM, z-batched (2 independent problems) ----------

#define LDK 40  // 32 + 8 pad shorts

struct GemmZArgs {
  const short* A[2];
  const short* Bt[2];
  const float* bias[2];
  short* Cb[2];
  int lda, ldc, M, Nc, K, kexp, do_relu;
};

__global__ __launch_bounds__(256) void mfma_gemmz_kernel(GemmZArgs g) {
  __shared__ __align__(16) short As[128 * LDK];
  __shared__ __align__(16) short Bs[128 * LDK];
  int z = blockIdx.z;
  const short* __restrict__ A = g.A[z];
  const short* __restrict__ Bt = g.Bt[z];
  int tid = threadIdx.x;
  int wave = tid >> 6, lane = tid & 63;
  int wr = (wave >> 1) * 64, wc = (wave & 1) * 64;
  int q = lane >> 4, m = lane & 15;
  int row0 = blockIdx.x * 128, col0 = blockIdx.y * 128;
  f32x4 acc[4][4] = {};
  for (int k0 = 0; k0 < g.K; k0 += 32) {
#pragma unroll
    for (int p = 0; p < 2; ++p) {
      int idx = p * 256 + tid;      // 0..511
      int r = idx >> 2, kc = (idx & 3) * 8;
      int gr = row0 + r;
      int kk = k0 + kc;
      int acol = g.kexp ? (kk + ((kk >> 7) << 7)) : kk;
      float4 v = make_float4(0.f, 0.f, 0.f, 0.f);
      if (gr < g.M) v = *(const float4*)(A + (size_t)gr * g.lda + acol);
      *(float4*)(As + r * LDK + kc) = v;
      float4 w = *(const float4*)(Bt + (size_t)(col0 + r) * g.K + kk);
      *(float4*)(Bs + r * LDK + kc) = w;
    }
    __syncthreads();
    bf16x8 af[4], bfr[4];
#pragma unroll
    for (int i = 0; i < 4; ++i) {
      af[i]  = *(const bf16x8*)(As + (wr + i * 16 + m) * LDK + q * 8);
      bfr[i] = *(const bf16x8*)(Bs + (wc + i * 16 + m) * LDK + q * 8);
    }
#pragma unroll
    for (int i = 0; i < 4; ++i)
#pragma unroll
      for (int j = 0; j < 4; ++j)
        acc[i][j] = __builtin_amdgcn_mfma_f32_16x16x32_bf16(af[i], bfr[j], acc[i][j], 0, 0, 0);
    __syncthreads();
  }
  const float* __restrict__ bias = g.bias[z];
  short* __restrict__ Cb = g.Cb[z];
#pragma unroll
  for (int i = 0; i < 4; ++i) {
#pragma unroll
    for (int r = 0; r < 4; ++r) {
      int rr = row0 + wr + i * 16 + q * 4 + r;
      if (rr >= g.M) continue;
#pragma unroll
      for (int j = 0; j < 4; ++j) {
        int cc = col0 + wc + j * 16 + m;
        float v = acc[i][j][r];
        if (bias) v += bias[cc];
        if (g.do_relu) v = fmaxf(v, 0.0f);
        Cb[(size_t)rr * g.ldc + cc] = f2b(v);
      }
    }
  }
}

// ---------------- wide-tile head GEMM + fused expmap0/proj epilogue ----------
// C[M,384] = A[M,384] @ Bt[384,384]^T, then per-row expmap0+proj, fp32 out.
// One block = 128 rows x ALL 384 cols (512 thr, 8 waves; wave = 16 rows).
// Row norm lives in one wave: acc[24] cols j*16+m  ->  24-term reg reduce +
// shfl_xor over the 16-lane m-group. Output split: rows<split -> Cf, else
// Cf2 + (row-split)*384.

struct Head2Args {
  const short* A[2];
  const short* Bt2;
  float* Cf[2];
  float* Cf2[2];
  int lda, M, split;
};

__global__ __launch_bounds__(512) void head2_kernel(Head2Args g) {
  __shared__ __align__(16) short As[128 * LDK];
  __shared__ __align__(16) short Bs[384 * LDK];
  int z = blockIdx.z;
  const short* __restrict__ A = g.A[z];
  const short* __restrict__ Bt = g.Bt2;
  int tid = threadIdx.x;
  int wave = tid >> 6, lane = tid & 63;
  int q = lane >> 4, m = lane & 15;
  int row0 = blockIdx.x * 128;
  f32x4 acc[24] = {};
  for (int k0 = 0; k0 < 384; k0 += 32) {
    {
      int r = tid >> 2, kc = (tid & 3) * 8;   // 128 rows x 32 k
      int gr = row0 + r;
      float4 v = make_float4(0.f, 0.f, 0.f, 0.f);
      if (gr < g.M) v = *(const float4*)(A + (size_t)gr * g.lda + k0 + kc);
      *(float4*)(As + r * LDK + kc) = v;
    }
#pragma unroll
    for (int p = 0; p < 3; ++p) {            // 384 cols x 32 k
      int idx = p * 512 + tid;
      int r = idx >> 2, kc = (idx & 3) * 8;
      float4 w0 = *(const float4*)(Bt + (size_t)r * 384 + k0 + kc);
      *(float4*)(Bs + r * LDK + kc) = w0;
    }
    __syncthreads();
    bf16x8 af = *(const bf16x8*)(As + (wave * 16 + m) * LDK + q * 8);
#pragma unroll
    for (int j = 0; j < 24; ++j) {
      bf16x8 bfr = *(const bf16x8*)(Bs + (j * 16 + m) * LDK + q * 8);
      acc[j] = __builtin_amdgcn_mfma_f32_16x16x32_bf16(af, bfr, acc[j], 0, 0, 0);
    }
    __syncthreads();
  }
  float* __restrict__ Cf = g.Cf[z];
  float* __restrict__ Cf2 = g.Cf2[z];
  const float maxn = 1.0f - 4e-3f;
#pragma unroll
  for (int r = 0; r < 4; ++r) {
    float s = 0.0f;
#pragma unroll
    for (int j = 0; j < 24; ++j) s += acc[j][r] * acc[j][r];
    s += __shfl_xor(s, 1, 64);
    s += __shfl_xor(s, 2, 64);
    s += __shfl_xor(s, 4, 64);
    s += __shfl_xor(s, 8, 64);
    int rr = row0 + wave * 16 + q * 4 + r;
    if (rr >= g.M) continue;
    float n = fmaxf(sqrtf(s), 1e-15f);
    float th = tanhf(n);
    float f = th / n;
    float n2 = fmaxf(th, 1e-15f);
    if (n2 > maxn) f *= maxn / n2;
    if (rr < g.split) {
#pragma unroll
      for (int j = 0; j < 24; ++j) Cf[(size_t)rr * 384 + j * 16 + m] = acc[j][r] * f;
    } else {
#pragma unroll
      for (int j = 0; j < 24; ++j) Cf2[(size_t)(rr - g.split) * 384 + j * 16 + m] = acc[j][r] * f;
    }
  }
}

// ---------------- global_add_pool over sorted batch, interleaved layout ----------

__global__ __launch_bounds__(768) void pool2_kernel(const short* __restrict__ NB,
                                                    const int* __restrict__ gptr,
                                                    short* __restrict__ GCb,
                                                    short* __restrict__ nbappend) {
  int g = blockIdx.x, t = threadIdx.x;  // t in [0,768)
  int s = gptr[g], e = gptr[g + 1];
  float acc = 0.0f;
  for (int i = s; i < e; ++i) acc += b2f(NB[(size_t)i * 768 + t]);
  short bv = f2b(acc);
  int l = t >> 8, rem = t & 255, b = rem >> 7, c = rem & 127;
  GCb[(size_t)g * 768 + b * 384 + l * 128 + c] = bv;
  nbappend[(size_t)g * 768 + t] = bv;
}

// ---------------- driver ----------------

extern "C" void kernel_launch(void* const* d_in, const int* in_sizes, int n_in,
                              void* d_out, int out_size, void* d_ws, size_t ws_size,
                              hipStream_t stream) {
  (void)in_sizes; (void)n_in; (void)out_size; (void)ws_size;
  const float* x   = (const float*)d_in[0];
  const float* x_s = (const float*)d_in[1];
  const int* src   = (const int*)d_in[2];
  const int* dst   = (const int*)d_in[3];
  const int* batch = (const int*)d_in[4];
  const float* Wf[3] = {(const float*)d_in[5], (const float*)d_in[6], (const float*)d_in[7]};
  const float* bf[3] = {(const float*)d_in[8], (const float*)d_in[9], (const float*)d_in[10]};
  const float* Wsb[3] = {(const float*)d_in[11], (const float*)d_in[12], (const float*)d_in[13]};
  const float* bs[3] = {(const float*)d_in[14], (const float*)d_in[15], (const float*)d_in[16]};
  const float* P1 = (const float*)d_in[17];
  const float* P2 = (const float*)d_in[18];
  const float* G1 = (const float*)d_in[19];
  const float* G2 = (const float*)d_in[20];
  float* out = (float*)d_out;

  char* w = (char*)d_ws;
  auto alloc = [&](size_t bytes) {
    char* p = w;
    w += (bytes + 255) & ~(size_t)255;
    return p;
  };
  // HIDb2 (head hidden, bf16, per-branch: 2 x M_ALL x 384) doubles as Ab
  // (logmap output, N x 256) -- lifetimes disjoint (Ab: logmap->agg L0).
  short* HIDb2 = (short*)alloc((size_t)2 * M_ALL * 384 * 2);
  short* Ab    = HIDb2;
  short* Xa    = (short*)alloc((size_t)N_NODES * 256 * 2);   // aggregated, interleaved
  short* NB    = (short*)alloc((size_t)M_ALL * 768 * 2);     // [row][l][branch][128]
  int* cnt     = (int*)alloc((size_t)N_NODES * 4);
  int* row_ptr = (int*)alloc((size_t)(N_NODES + 1) * 4);
  int* cursor  = (int*)alloc((size_t)N_NODES * 4);
  float* dinv  = (float*)alloc((size_t)N_NODES * 4);
  int* col     = (int*)alloc((size_t)N_EDGES * 4);
  float* ew    = (float*)alloc((size_t)N_EDGES * 4);
  int* gptr    = (int*)alloc((size_t)(N_GRAPHS + 1) * 4);
  int* bsum    = (int*)alloc(256 * 4);
  short* GCb   = (short*)alloc((size_t)N_GRAPHS * 768 * 2);
  short* GHb   = (short*)alloc((size_t)N_GRAPHS * 384 * 2);
  short* P1t   = (short*)alloc((size_t)EDIM * EDIM * 2);
  short* P2t   = (short*)alloc((size_t)EDIM * EDIM * 2);
  short* G1t   = (short*)alloc((size_t)768 * EDIM * 2);
  short* G2t   = (short*)alloc((size_t)EDIM * EDIM * 2);
  short* Wft[3], *Wst[3];
  for (int l = 0; l < 3; ++l) {
    Wft[l] = (short*)alloc((size_t)128 * 128 * 2);
    Wst[l] = (short*)alloc((size_t)128 * 128 * 2);
  }

  // ---- weight convert (independent of graph) ----
  {
    WcArgs wa;
    wa.seg[0] = {P1, P1t, EDIM, EDIM};
    wa.seg[1] = {P2, P2t, EDIM, EDIM};
    wa.seg[2] = {G1, G1t, 768, EDIM};
    wa.seg[3] = {G2, G2t, EDIM, EDIM};
    for (int l = 0; l < 3; ++l) {
      wa.seg[4 + l] = {Wf[l], Wft[l], 128, 128};
      wa.seg[7 + l] = {Wsb[l], Wst[l], 128, 128};
    }
    wconv_all_kernel<<<dim3((768 * EDIM + 255) / 256, 10), 256, 0, stream>>>(wa);
  }

  // ---- graph structure: 5 launches ----
  init_kernel<<<SCAN_NB, SCAN_BS, 0, stream>>>(batch, cnt, gptr);
  hist_kernel<<<(N_EDGES + 255) / 256, 256, 0, stream>>>(dst, cnt);
  scan1_kernel<<<SCAN_NB, SCAN_BS, 0, stream>>>(cnt, row_ptr, bsum);
  scan3_kernel<<<SCAN_NB, SCAN_BS, 0, stream>>>(cnt, bsum, row_ptr, cursor, dinv);
  scatter_kernel<<<(N_EDGES + 255) / 256, 256, 0, stream>>>(src, dst, dinv, cursor, col, ew);

  const size_t OUT0 = 0;
  const size_t OUT1 = (size_t)N_GRAPHS * EDIM;
  const size_t OUT2 = OUT1 + (size_t)N_GRAPHS * EDIM;
  const size_t OUT3 = OUT2 + (size_t)N_NODES * EDIM;

  const int gx_layer = (N_NODES + 127) / 128;   // 391
  const int gx_mfma  = (M_ALL + 127) / 128;     // 395
  const int gx_agg   = (N_NODES + 3) / 4;       // 12500

  // ---- logmap both branches -> interleaved Ab ----
  logmap2_kernel<<<(2 * N_NODES + 3) / 4, 256, 0, stream>>>(x, x_s, Ab);

  // ---- 3 GCN layers, both branches per launch ----
  const short* cur = Ab;
  int clda = 256;
  for (int l = 0; l < 3; ++l) {
    agg2_kernel<<<gx_agg, 256, 0, stream>>>(cur, clda, dinv, row_ptr, col, ew, Xa);
    GemmZArgs ga = {};
    ga.A[0] = Xa;        ga.A[1] = Xa + 128;
    ga.Bt[0] = Wft[l];   ga.Bt[1] = Wst[l];
    ga.bias[0] = bf[l];  ga.bias[1] = bs[l];
    ga.Cb[0] = NB + l * 256;        ga.Cb[1] = NB + l * 256 + 128;
    ga.lda = 256; ga.ldc = 768; ga.M = N_NODES; ga.Nc = 128; ga.K = 128;
    ga.kexp = 0; ga.do_relu = 1;
    mfma_gemmz_kernel<<<dim3(gx_layer, 1, 2), 256, 0, stream>>>(ga);
    cur = NB + l * 256;
    clda = 768;
  }

  // ---- pool (both branches) + append pooled rows to NB ----
  pool2_kernel<<<N_GRAPHS, 768, 0, stream>>>(NB, gptr, GCb, NB + (size_t)N_NODES * 768);

  // ---- g head: relu(gcat@G1) bf16 -> GHb, then wide-tile @G2 + fused exp/proj ----
  const int gx_g = (N_GRAPHS + 127) / 128;  // 4
  {
    GemmZArgs g1 = {};
    g1.A[0] = g1.A[1] = GCb;
    g1.Bt[0] = g1.Bt[1] = G1t;
    g1.Cb[0] = g1.Cb[1] = GHb;
    g1.lda = 768; g1.ldc = 384; g1.M = N_GRAPHS; g1.Nc = EDIM; g1.K = 768;
    g1.kexp = 0; g1.do_relu = 1;
    mfma_gemmz_kernel<<<dim3(gx_g, 3, 1), 256, 0, stream>>>(g1);

    Head2Args g2 = {};
    g2.A[0] = g2.A[1] = GHb;
    g2.Bt2 = G2t;
    g2.Cf[0] = g2.Cf[1] = out + OUT0;
    g2.Cf2[0] = g2.Cf2[1] = out + OUT0;
    g2.lda = 384; g2.M = N_GRAPHS; g2.split = 1 << 30;
    head2_kernel<<<dim3(gx_g, 1, 1), 512, 0, stream>>>(g2);
  }

  // ---- node+graph MLP heads: h1 (bf16 hidden), then wide-tile h2 + fused exp/proj ----
  float* ghead_out[2] = {out + OUT1, out + OUT3};
  float* node_out[2]  = {out + OUT2, out + OUT3 + (size_t)N_GRAPHS * EDIM};
  {
    GemmZArgs h1 = {};
    h1.A[0] = NB;                 h1.A[1] = NB + 128;
    h1.Bt[0] = h1.Bt[1] = P1t;
    h1.Cb[0] = HIDb2;             h1.Cb[1] = HIDb2 + (size_t)M_ALL * 384;
    h1.lda = 768; h1.ldc = 384; h1.M = M_ALL; h1.Nc = EDIM; h1.K = EDIM;
    h1.kexp = 1; h1.do_relu = 1;
    mfma_gemmz_kernel<<<dim3(gx_mfma, 3, 2), 256, 0, stream>>>(h1);

    Head2Args h2 = {};
    h2.A[0] = HIDb2;              h2.A[1] = HIDb2 + (size_t)M_ALL * 384;
    h2.Bt2 = P2t;
    h2.Cf[0] = node_out[0];       h2.Cf[1] = node_out[1];
    h2.Cf2[0] = ghead_out[0];     h2.Cf2[1] = ghead_out[1];
    h2.lda = 384; h2.M = M_ALL; h2.split = N_NODES;
    head2_kernel<<<dim3(gx_mfma, 1, 2), 512, 0, stream>>>(h2);
  }
}

// Round 6
// 766.579 us; speedup vs baseline: 1.2975x; 1.0051x over previous
//
#include <hip/hip_runtime.h>
#include <math.h>

#define N_NODES 50000
#define N_EDGES 600000
#define N_GRAPHS 512
#define F_IN 128
#define D_HID 128
#define EDIM 384
#define M_ALL (N_NODES + N_GRAPHS)  // node rows + appended pooled graph rows

typedef __attribute__((ext_vector_type(8))) short bf16x8;
typedef __attribute__((ext_vector_type(4))) float f32x4;

static __device__ __forceinline__ float wave_reduce_sum(float s) {
#pragma unroll
  for (int off = 32; off > 0; off >>= 1) s += __shfl_xor(s, off, 64);
  return s;
}

static __device__ __forceinline__ int wave_reduce_sum_i(int s) {
#pragma unroll
  for (int off = 32; off > 0; off >>= 1) s += __shfl_xor(s, off, 64);
  return s;
}

static __device__ __forceinline__ short f2b(float f) {
  unsigned u = __float_as_uint(f);
  unsigned r = (u + 0x7FFFu + ((u >> 16) & 1u)) >> 16;
  return (short)r;
}

static __device__ __forceinline__ float b2f(short s) {
  return __uint_as_float(((unsigned)(unsigned short)s) << 16);
}

// ---------------- graph preprocessing ----------------

#define SCAN_BS 256
#define SCAN_NB ((N_NODES + SCAN_BS - 1) / SCAN_BS)  // 196

// zero cnt + compute gptr (binary search over sorted batch), one launch
__global__ __launch_bounds__(SCAN_BS) void init_kernel(const int* __restrict__ batch,
                                                       int* __restrict__ cnt,
                                                       int* __restrict__ gptr) {
  int i = blockIdx.x * SCAN_BS + threadIdx.x;
  if (i < N_NODES) cnt[i] = 0;
  if (i <= N_GRAPHS) {
    int lo = 0, hi = N_NODES;
    while (lo < hi) { int mid = (lo + hi) >> 1; if (batch[mid] < i) lo = mid + 1; else hi = mid; }
    gptr[i] = lo;
  }
}

__global__ void hist_kernel(const int* __restrict__ dst, int* __restrict__ cnt) {
  int i = blockIdx.x * blockDim.x + threadIdx.x;
  if (i < N_EDGES) atomicAdd(&cnt[dst[i]], 1);
}

__global__ __launch_bounds__(SCAN_BS) void scan1_kernel(const int* __restrict__ cnt,
                                                        int* __restrict__ row_ptr,
                                                        int* __restrict__ bsum) {
  __shared__ int wsum[4];
  int tid = threadIdx.x, lane = tid & 63, wid = tid >> 6;
  int idx = blockIdx.x * SCAN_BS + tid;
  int v = (idx < N_NODES) ? cnt[idx] : 0;
  int x = v;
#pragma unroll
  for (int off = 1; off < 64; off <<= 1) {
    int t = __shfl_up(x, off, 64);
    if (lane >= off) x += t;
  }
  if (lane == 63) wsum[wid] = x;
  __syncthreads();
  int pre = 0, tot = 0;
#pragma unroll
  for (int w = 0; w < 4; ++w) { int s = wsum[w]; tot += s; if (w < wid) pre += s; }
  if (idx < N_NODES) row_ptr[idx + 1] = x + pre;  // block-local inclusive
  if (tid == 0) bsum[blockIdx.x] = tot;
}

// scan3 with fused scan2 (local re-reduction of bsum prefix) + fused dinv
__global__ __launch_bounds__(SCAN_BS) void scan3_kernel(const int* __restrict__ cnt,
                                                        const int* __restrict__ bsum,
                                                        int* __restrict__ row_ptr,
                                                        int* __restrict__ cursor,
                                                        float* __restrict__ dinv) {
  __shared__ int ws[4];
  int tid = threadIdx.x, lane = tid & 63, wid = tid >> 6;
  int v = 0;
  if (tid < SCAN_NB && tid < blockIdx.x) v = bsum[tid];
  v = wave_reduce_sum_i(v);
  if (lane == 0) ws[wid] = v;
  __syncthreads();
  int boff = ws[0] + ws[1] + ws[2] + ws[3];
  int idx = blockIdx.x * SCAN_BS + tid;
  if (idx >= N_NODES) return;
  int val = row_ptr[idx + 1] + boff;
  row_ptr[idx + 1] = val;
  int c = cnt[idx];
  cursor[idx] = val - c;
  dinv[idx] = 1.0f / sqrtf((float)(c + 1));
  if (idx == 0) row_ptr[0] = 0;
}

__global__ void scatter_kernel(const int* __restrict__ src, const int* __restrict__ dst,
                               const float* __restrict__ dinv, int* __restrict__ cursor,
                               int* __restrict__ col, float* __restrict__ ew) {
  int e = blockIdx.x * blockDim.x + threadIdx.x;
  if (e >= N_EDGES) return;
  int s = src[e], d = dst[e];
  int pos = atomicAdd(&cursor[d], 1);
  col[pos] = s;
  ew[pos] = dinv[s] * dinv[d];
}

// ---------------- combined weight convert+transpose (10 matrices, 1 launch) ----

struct WcSeg { const float* W; short* Wt; int K; int Nc; };
struct WcArgs { WcSeg seg[10]; };

__global__ void wconv_all_kernel(WcArgs a) {
  int sidx = blockIdx.y;
  WcSeg s = a.seg[sidx];
  int i = blockIdx.x * blockDim.x + threadIdx.x;
  if (i >= s.K * s.Nc) return;
  int k = i / s.Nc, n = i - k * s.Nc;
  s.Wt[(size_t)n * s.K + k] = f2b(s.W[i]);
}

// ---------------- logmap0 for BOTH branches -> interleaved Ab[node][f:128|s:128] ----

__global__ __launch_bounds__(256) void logmap2_kernel(const float* __restrict__ x,
                                                      const float* __restrict__ x_s,
                                                      short* __restrict__ Ab) {
  int w = blockIdx.x * 4 + (threadIdx.x >> 6);
  int lane = threadIdx.x & 63;
  if (w >= 2 * N_NODES) return;
  int br = (w >= N_NODES) ? 1 : 0;
  int row = br ? (w - N_NODES) : w;
  const float* xr = (br ? x_s : x) + (size_t)row * F_IN;
  float2 v = *(const float2*)(xr + lane * 2);
  float s = wave_reduce_sum(v.x * v.x + v.y * v.y);
  float n = sqrtf(s);
  float nc = fmaxf(n, 1e-15f);
  float f = atanhf(fminf(nc, 0.9999999f)) / nc;
  short2 o; o.x = f2b(v.x * f); o.y = f2b(v.y * f);
  *(short2*)(Ab + (size_t)row * 256 + br * 128 + lane * 2) = o;
}

// ---------------- CSR aggregation, both branches per gather (512B rows) ----------

__global__ __launch_bounds__(256) void agg2_kernel(const short* __restrict__ Xin, int lda,
                                                   const float* __restrict__ dinv,
                                                   const int* __restrict__ row_ptr,
                                                   const int* __restrict__ col,
                                                   const float* __restrict__ ew,
                                                   short* __restrict__ Xa) {
  int node = blockIdx.x * 4 + (threadIdx.x >> 6);
  int lane = threadIdx.x & 63;
  if (node >= N_NODES) return;
  float di = dinv[node];
  float wsf = di * di;
  short4 sv = *(const short4*)(Xin + (size_t)node * lda + lane * 4);
  float a0 = b2f(sv.x) * wsf, a1 = b2f(sv.y) * wsf, a2 = b2f(sv.z) * wsf, a3 = b2f(sv.w) * wsf;
  int s = row_ptr[node], e = row_ptr[node + 1];
  int j = s;
  for (; j + 4 <= e; j += 4) {
    int c0 = col[j], c1 = col[j + 1], c2 = col[j + 2], c3 = col[j + 3];
    float w0 = ew[j], w1 = ew[j + 1], w2 = ew[j + 2], w3 = ew[j + 3];
    short4 v0 = *(const short4*)(Xin + (size_t)c0 * lda + lane * 4);
    short4 v1 = *(const short4*)(Xin + (size_t)c1 * lda + lane * 4);
    short4 v2 = *(const short4*)(Xin + (size_t)c2 * lda + lane * 4);
    short4 v3 = *(const short4*)(Xin + (size_t)c3 * lda + lane * 4);
    a0 += b2f(v0.x) * w0; a1 += b2f(v0.y) * w0; a2 += b2f(v0.z) * w0; a3 += b2f(v0.w) * w0;
    a0 += b2f(v1.x) * w1; a1 += b2f(v1.y) * w1; a2 += b2f(v1.z) * w1; a3 += b2f(v1.w) * w1;
    a0 += b2f(v2.x) * w2; a1 += b2f(v2.y) * w2; a2 += b2f(v2.z) * w2; a3 += b2f(v2.w) * w2;
    a0 += b2f(v3.x) * w3; a1 += b2f(v3.y) * w3; a2 += b2f(v3.z) * w3; a3 += b2f(v3.w) * w3;
  }
  for (; j < e; ++j) {
    float w0 = ew[j];
    short4 v0 = *(const short4*)(Xin + (size_t)col[j] * lda + lane * 4);
    a0 += b2f(v0.x) * w0; a1 += b2f(v0.y) * w0; a2 += b2f(v0.z) * w0; a3 += b2f(v0.w) * w0;
  }
  short4 o; o.x = f2b(a0); o.y = f2b(a1); o.z = f2b(a2); o.w = f2b(a3);
  *(short4*)(Xa + (size_t)node * 256 + lane * 4) = o;
}

// ---------------- bf16 MFMA GEMM, z-batched (2 independent problems) ----------

#define LDK 40  // 32 + 8 pad shorts

struct GemmZArgs {
  const short* A[2];
  const short* Bt[2];
  const float* bias[2];
  short* Cb[2];
  int lda, ldc, M, Nc, K, kexp, do_relu;
};

__global__ __launch_bounds__(256) void mfma_gemmz_kernel(GemmZArgs g) {
  __shared__ __align__(16) short As[128 * LDK];
  __shared__ __align__(16) short Bs[128 * LDK];
  int z = blockIdx.z;
  const short* __restrict__ A = g.A[z];
  const short* __restrict__ Bt = g.Bt[z];
  int tid = threadIdx.x;
  int wave = tid >> 6, lane = tid & 63;
  int wr = (wave >> 1) * 64, wc = (wave & 1) * 64;
  int q = lane >> 4, m = lane & 15;
  int row0 = blockIdx.x * 128, col0 = blockIdx.y * 128;
  f32x4 acc[4][4] = {};
  for (int k0 = 0; k0 < g.K; k0 += 32) {
#pragma unroll
    for (int p = 0; p < 2; ++p) {
      int idx = p * 256 + tid;      // 0..511
      int r = idx >> 2, kc = (idx & 3) * 8;
      int gr = row0 + r;
      int kk = k0 + kc;
      int acol = g.kexp ? (kk + ((kk >> 7) << 7)) : kk;
      float4 v = make_float4(0.f, 0.f, 0.f, 0.f);
      if (gr < g.M) v = *(const float4*)(A + (size_t)gr * g.lda + acol);
      *(float4*)(As + r * LDK + kc) = v;
      float4 w = *(const float4*)(Bt + (size_t)(col0 + r) * g.K + kk);
      *(float4*)(Bs + r * LDK + kc) = w;
    }
    __syncthreads();
    bf16x8 af[4], bfr[4];
#pragma unroll
    for (int i = 0; i < 4; ++i) {
      af[i]  = *(const bf16x8*)(As + (wr + i * 16 + m) * LDK + q * 8);
      bfr[i] = *(const bf16x8*)(Bs + (wc + i * 16 + m) * LDK + q * 8);
    }
#pragma unroll
    for (int i = 0; i < 4; ++i)
#pragma unroll
      for (int j = 0; j < 4; ++j)
        acc[i][j] = __builtin_amdgcn_mfma_f32_16x16x32_bf16(af[i], bfr[j], acc[i][j], 0, 0, 0);
    __syncthreads();
  }
  const float* __restrict__ bias = g.bias[z];
  short* __restrict__ Cb = g.Cb[z];
#pragma unroll
  for (int i = 0; i < 4; ++i) {
#pragma unroll
    for (int r = 0; r < 4; ++r) {
      int rr = row0 + wr + i * 16 + q * 4 + r;
      if (rr >= g.M) continue;
#pragma unroll
      for (int j = 0; j < 4; ++j) {
        int cc = col0 + wc + j * 16 + m;
        float v = acc[i][j][r];
        if (bias) v += bias[cc];
        if (g.do_relu) v = fmaxf(v, 0.0f);
        Cb[(size_t)rr * g.ldc + cc] = f2b(v);
      }
    }
  }
}

// ---------------- fused 2-layer MLP head + expmap0/proj epilogue ----------------
// out = expproj( relu(A @ B1^T) @ B2^T ), per block: 128 rows x full 384x384.
// 512 thr, 8 waves; wave = 2 row-frags (16 rows each) x 12 col-frags (cg half).
// Stage 1 acc in regs -> relu -> bf16 hidden in LDS H; stage 2 reads H as the
// MFMA A operand; row norm = 12-term reg reduce + m-group shfl + cross-cg LDS.
// Output split: rows<split -> Cf (stride 384), else Cf2 + (row-split)*384.

#define HLD 392  // 384 + 8 pad shorts

struct Mlp2Args {
  const short* A[2];
  const short* B1;     // [384][K1]  (stage-1 weights, row = out col)
  const short* B2;     // [384][384]
  float* Cf[2];
  float* Cf2[2];
  int lda, M, K1, kexp, split;
};

__global__ __launch_bounds__(512, 2) void mlp2_kernel(Mlp2Args g) {
  __shared__ __align__(16) short As[128 * LDK];
  __shared__ __align__(16) short Bs[384 * LDK];
  __shared__ __align__(16) short H[128 * HLD];
  __shared__ float nsum[128][2];
  int z = blockIdx.z;
  const short* __restrict__ A = g.A[z];
  int tid = threadIdx.x;
  int wave = tid >> 6, lane = tid & 63;
  int q = lane >> 4, m = lane & 15;
  int rbase = (wave & 3) * 32;   // 2 row-frags: rbase, rbase+16
  int cg = wave >> 2;            // col half: cols cg*192 .. +191
  int row0 = blockIdx.x * 128;
  f32x4 acc[2][12] = {};
  // ---- stage 1: hidden = relu(A @ B1^T), K = K1 ----
  for (int k0 = 0; k0 < g.K1; k0 += 32) {
    {
      int r = tid >> 2, kc = (tid & 3) * 8;   // 128 rows x 32 k
      int gr = row0 + r;
      int kk = k0 + kc;
      int acol = g.kexp ? (kk + ((kk >> 7) << 7)) : kk;
      float4 v = make_float4(0.f, 0.f, 0.f, 0.f);
      if (gr < g.M) v = *(const float4*)(A + (size_t)gr * g.lda + acol);
      *(float4*)(As + r * LDK + kc) = v;
    }
#pragma unroll
    for (int p = 0; p < 3; ++p) {            // 384 hidden cols x 32 k
      int idx = p * 512 + tid;
      int r = idx >> 2, kc = (idx & 3) * 8;
      float4 w0 = *(const float4*)(g.B1 + (size_t)r * g.K1 + k0 + kc);
      *(float4*)(Bs + r * LDK + kc) = w0;
    }
    __syncthreads();
    bf16x8 af0 = *(const bf16x8*)(As + (rbase + m) * LDK + q * 8);
    bf16x8 af1 = *(const bf16x8*)(As + (rbase + 16 + m) * LDK + q * 8);
#pragma unroll
    for (int j = 0; j < 12; ++j) {
      bf16x8 bfr = *(const bf16x8*)(Bs + (cg * 192 + j * 16 + m) * LDK + q * 8);
      acc[0][j] = __builtin_amdgcn_mfma_f32_16x16x32_bf16(af0, bfr, acc[0][j], 0, 0, 0);
      acc[1][j] = __builtin_amdgcn_mfma_f32_16x16x32_bf16(af1, bfr, acc[1][j], 0, 0, 0);
    }
    __syncthreads();
  }
  // ---- relu + bf16 hidden -> LDS H ----
#pragma unroll
  for (int sub = 0; sub < 2; ++sub)
#pragma unroll
    for (int j = 0; j < 12; ++j)
#pragma unroll
      for (int r = 0; r < 4; ++r)
        H[(rbase + sub * 16 + q * 4 + r) * HLD + cg * 192 + j * 16 + m] =
            f2b(fmaxf(acc[sub][j][r], 0.0f));
#pragma unroll
  for (int sub = 0; sub < 2; ++sub)
#pragma unroll
    for (int j = 0; j < 12; ++j) acc[sub][j] = (f32x4){0.f, 0.f, 0.f, 0.f};
  // ---- stage 2: out = H @ B2^T, K = 384 ----
  for (int k0 = 0; k0 < 384; k0 += 32) {
#pragma unroll
    for (int p = 0; p < 3; ++p) {
      int idx = p * 512 + tid;
      int r = idx >> 2, kc = (idx & 3) * 8;
      float4 w0 = *(const float4*)(g.B2 + (size_t)r * 384 + k0 + kc);
      *(float4*)(Bs + r * LDK + kc) = w0;
    }
    __syncthreads();   // also orders H writes (first iter) before H reads
    bf16x8 af0 = *(const bf16x8*)(H + (rbase + m) * HLD + k0 + q * 8);
    bf16x8 af1 = *(const bf16x8*)(H + (rbase + 16 + m) * HLD + k0 + q * 8);
#pragma unroll
    for (int j = 0; j < 12; ++j) {
      bf16x8 bfr = *(const bf16x8*)(Bs + (cg * 192 + j * 16 + m) * LDK + q * 8);
      acc[0][j] = __builtin_amdgcn_mfma_f32_16x16x32_bf16(af0, bfr, acc[0][j], 0, 0, 0);
      acc[1][j] = __builtin_amdgcn_mfma_f32_16x16x32_bf16(af1, bfr, acc[1][j], 0, 0, 0);
    }
    __syncthreads();
  }
  // ---- per-row norm partials (this wave's 192-col half) ----
#pragma unroll
  for (int sub = 0; sub < 2; ++sub) {
#pragma unroll
    for (int r = 0; r < 4; ++r) {
      float s = 0.0f;
#pragma unroll
      for (int j = 0; j < 12; ++j) s += acc[sub][j][r] * acc[sub][j][r];
      s += __shfl_xor(s, 1, 64);
      s += __shfl_xor(s, 2, 64);
      s += __shfl_xor(s, 4, 64);
      s += __shfl_xor(s, 8, 64);
      if (m == 0) nsum[rbase + sub * 16 + q * 4 + r][cg] = s;
    }
  }
  __syncthreads();
  // ---- expmap0 + proj + store ----
  const float maxn = 1.0f - 4e-3f;
  float* __restrict__ Cf = g.Cf[z];
  float* __restrict__ Cf2 = g.Cf2[z];
#pragma unroll
  for (int sub = 0; sub < 2; ++sub) {
#pragma unroll
    for (int r = 0; r < 4; ++r) {
      int rl = rbase + sub * 16 + q * 4 + r;
      int rr = row0 + rl;
      if (rr >= g.M) continue;
      float s = nsum[rl][0] + nsum[rl][1];
      float n = fmaxf(sqrtf(s), 1e-15f);
      float th = tanhf(n);
      float f = th / n;
      float n2 = fmaxf(th, 1e-15f);
      if (n2 > maxn) f *= maxn / n2;
      if (rr < g.split) {
#pragma unroll
        for (int j = 0; j < 12; ++j)
          Cf[(size_t)rr * 384 + cg * 192 + j * 16 + m] = acc[sub][j][r] * f;
      } else {
#pragma unroll
        for (int j = 0; j < 12; ++j)
          Cf2[(size_t)(rr - g.split) * 384 + cg * 192 + j * 16 + m] = acc[sub][j][r] * f;
      }
    }
  }
}

// ---------------- global_add_pool over sorted batch, interleaved layout ----------

__global__ __launch_bounds__(768) void pool2_kernel(const short* __restrict__ NB,
                                                    const int* __restrict__ gptr,
                                                    short* __restrict__ GCb,
                                                    short* __restrict__ nbappend) {
  int g = blockIdx.x, t = threadIdx.x;  // t in [0,768)
  int s = gptr[g], e = gptr[g + 1];
  float acc = 0.0f;
  for (int i = s; i < e; ++i) acc += b2f(NB[(size_t)i * 768 + t]);
  short bv = f2b(acc);
  int l = t >> 8, rem = t & 255, b = rem >> 7, c = rem & 127;
  GCb[(size_t)g * 768 + b * 384 + l * 128 + c] = bv;
  nbappend[(size_t)g * 768 + t] = bv;
}

// ---------------- driver ----------------

extern "C" void kernel_launch(void* const* d_in, const int* in_sizes, int n_in,
                              void* d_out, int out_size, void* d_ws, size_t ws_size,
                              hipStream_t stream) {
  (void)in_sizes; (void)n_in; (void)out_size; (void)ws_size;
  const float* x   = (const float*)d_in[0];
  const float* x_s = (const float*)d_in[1];
  const int* src   = (const int*)d_in[2];
  const int* dst   = (const int*)d_in[3];
  const int* batch = (const int*)d_in[4];
  const float* Wf[3] = {(const float*)d_in[5], (const float*)d_in[6], (const float*)d_in[7]};
  const float* bf[3] = {(const float*)d_in[8], (const float*)d_in[9], (const float*)d_in[10]};
  const float* Wsb[3] = {(const float*)d_in[11], (const float*)d_in[12], (const float*)d_in[13]};
  const float* bs[3] = {(const float*)d_in[14], (const float*)d_in[15], (const float*)d_in[16]};
  const float* P1 = (const float*)d_in[17];
  const float* P2 = (const float*)d_in[18];
  const float* G1 = (const float*)d_in[19];
  const float* G2 = (const float*)d_in[20];
  float* out = (float*)d_out;

  char* w = (char*)d_ws;
  auto alloc = [&](size_t bytes) {
    char* p = w;
    w += (bytes + 255) & ~(size_t)255;
    return p;
  };
  short* Ab    = (short*)alloc((size_t)N_NODES * 256 * 2);   // logmap out, interleaved
  short* Xa    = (short*)alloc((size_t)N_NODES * 256 * 2);   // aggregated, interleaved
  short* NB    = (short*)alloc((size_t)M_ALL * 768 * 2);     // [row][l][branch][128]
  int* cnt     = (int*)alloc((size_t)N_NODES * 4);
  int* row_ptr = (int*)alloc((size_t)(N_NODES + 1) * 4);
  int* cursor  = (int*)alloc((size_t)N_NODES * 4);
  float* dinv  = (float*)alloc((size_t)N_NODES * 4);
  int* col     = (int*)alloc((size_t)N_EDGES * 4);
  float* ew    = (float*)alloc((size_t)N_EDGES * 4);
  int* gptr    = (int*)alloc((size_t)(N_GRAPHS + 1) * 4);
  int* bsum    = (int*)alloc(256 * 4);
  short* GCb   = (short*)alloc((size_t)N_GRAPHS * 768 * 2);
  short* P1t   = (short*)alloc((size_t)EDIM * EDIM * 2);
  short* P2t   = (short*)alloc((size_t)EDIM * EDIM * 2);
  short* G1t   = (short*)alloc((size_t)768 * EDIM * 2);
  short* G2t   = (short*)alloc((size_t)EDIM * EDIM * 2);
  short* Wft[3], *Wst[3];
  for (int l = 0; l < 3; ++l) {
    Wft[l] = (short*)alloc((size_t)128 * 128 * 2);
    Wst[l] = (short*)alloc((size_t)128 * 128 * 2);
  }

  // ---- weight convert (independent of graph) ----
  {
    WcArgs wa;
    wa.seg[0] = {P1, P1t, EDIM, EDIM};
    wa.seg[1] = {P2, P2t, EDIM, EDIM};
    wa.seg[2] = {G1, G1t, 768, EDIM};
    wa.seg[3] = {G2, G2t, EDIM, EDIM};
    for (int l = 0; l < 3; ++l) {
      wa.seg[4 + l] = {Wf[l], Wft[l], 128, 128};
      wa.seg[7 + l] = {Wsb[l], Wst[l], 128, 128};
    }
    wconv_all_kernel<<<dim3((768 * EDIM + 255) / 256, 10), 256, 0, stream>>>(wa);
  }

  // ---- graph structure: 5 launches ----
  init_kernel<<<SCAN_NB, SCAN_BS, 0, stream>>>(batch, cnt, gptr);
  hist_kernel<<<(N_EDGES + 255) / 256, 256, 0, stream>>>(dst, cnt);
  scan1_kernel<<<SCAN_NB, SCAN_BS, 0, stream>>>(cnt, row_ptr, bsum);
  scan3_kernel<<<SCAN_NB, SCAN_BS, 0, stream>>>(cnt, bsum, row_ptr, cursor, dinv);
  scatter_kernel<<<(N_EDGES + 255) / 256, 256, 0, stream>>>(src, dst, dinv, cursor, col, ew);

  const size_t OUT0 = 0;
  const size_t OUT1 = (size_t)N_GRAPHS * EDIM;
  const size_t OUT2 = OUT1 + (size_t)N_GRAPHS * EDIM;
  const size_t OUT3 = OUT2 + (size_t)N_NODES * EDIM;

  const int gx_layer = (N_NODES + 127) / 128;   // 391
  const int gx_mfma  = (M_ALL + 127) / 128;     // 395
  const int gx_agg   = (N_NODES + 3) / 4;       // 12500

  // ---- logmap both branches -> interleaved Ab ----
  logmap2_kernel<<<(2 * N_NODES + 3) / 4, 256, 0, stream>>>(x, x_s, Ab);

  // ---- 3 GCN layers, both branches per launch ----
  const short* cur = Ab;
  int clda = 256;
  for (int l = 0; l < 3; ++l) {
    agg2_kernel<<<gx_agg, 256, 0, stream>>>(cur, clda, dinv, row_ptr, col, ew, Xa);
    GemmZArgs ga = {};
    ga.A[0] = Xa;        ga.A[1] = Xa + 128;
    ga.Bt[0] = Wft[l];   ga.Bt[1] = Wst[l];
    ga.bias[0] = bf[l];  ga.bias[1] = bs[l];
    ga.Cb[0] = NB + l * 256;        ga.Cb[1] = NB + l * 256 + 128;
    ga.lda = 256; ga.ldc = 768; ga.M = N_NODES; ga.Nc = 128; ga.K = 128;
    ga.kexp = 0; ga.do_relu = 1;
    mfma_gemmz_kernel<<<dim3(gx_layer, 1, 2), 256, 0, stream>>>(ga);
    cur = NB + l * 256;
    clda = 768;
  }

  // ---- pool (both branches) + append pooled rows to NB ----
  pool2_kernel<<<N_GRAPHS, 768, 0, stream>>>(NB, gptr, GCb, NB + (size_t)N_NODES * 768);

  // ---- g head, fully fused: expproj(relu(gcat@G1)@G2) -> out0 ----
  {
    Mlp2Args gh = {};
    gh.A[0] = gh.A[1] = GCb;
    gh.B1 = G1t; gh.B2 = G2t;
    gh.Cf[0] = gh.Cf[1] = out + OUT0;
    gh.Cf2[0] = gh.Cf2[1] = out + OUT0;
    gh.lda = 768; gh.M = N_GRAPHS; gh.K1 = 768; gh.kexp = 0; gh.split = 1 << 30;
    mlp2_kernel<<<dim3((N_GRAPHS + 127) / 128, 1, 1), 512, 0, stream>>>(gh);
  }

  // ---- node+graph MLP heads, fully fused, both branches z-batched ----
  {
    Mlp2Args h = {};
    h.A[0] = NB;                  h.A[1] = NB + 128;
    h.B1 = P1t; h.B2 = P2t;
    h.Cf[0] = out + OUT2;         h.Cf[1] = out + OUT3 + (size_t)N_GRAPHS * EDIM;
    h.Cf2[0] = out + OUT1;        h.Cf2[1] = out + OUT3;
    h.lda = 768; h.M = M_ALL; h.K1 = EDIM; h.kexp = 1; h.split = N_NODES;
    mlp2_kernel<<<dim3(gx_mfma, 1, 2), 512, 0, stream>>>(h);
  }
}